// Round 2
// baseline (2905.096 us; speedup 1.0000x reference)
//
#include <hip/hip_runtime.h>
#include <cstdint>
#include <cstddef>

#define B_DIM 4
#define L_DIM 2048
#define H_DIM 1024
#define D_DIM 2048
#define N_STATE 16
#define TOKENS (B_DIM * L_DIM)   // 8192

__device__ __forceinline__ float sigmoidf_(float x) { return 1.f / (1.f + __expf(-x)); }
__device__ __forceinline__ float softplusf_(float x) {
  return fmaxf(x, 0.f) + log1pf(__expf(-fabsf(x)));
}

// ---------------- LayerNorm: one block per token ----------------
__global__ __launch_bounds__(256) void ln_kernel(const float* __restrict__ x,
    const float* __restrict__ gamma, const float* __restrict__ beta,
    float* __restrict__ out) {
  int row = blockIdx.x;
  int t = threadIdx.x;
  const float* px = x + (size_t)row * H_DIM;
  float4 v = *(const float4*)(px + t * 4);
  float s  = v.x + v.y + v.z + v.w;
  float ss = v.x * v.x + v.y * v.y + v.z * v.z + v.w * v.w;
  for (int off = 32; off > 0; off >>= 1) {
    s  += __shfl_down(s, off);
    ss += __shfl_down(ss, off);
  }
  __shared__ float red[8];
  __shared__ float stats[2];
  int wave = t >> 6, lane = t & 63;
  if (lane == 0) { red[wave] = s; red[4 + wave] = ss; }
  __syncthreads();
  if (t == 0) {
    float S  = red[0] + red[1] + red[2] + red[3];
    float SS = red[4] + red[5] + red[6] + red[7];
    float mu = S / H_DIM;
    float var = SS / H_DIM - mu * mu;
    stats[0] = mu;
    stats[1] = rsqrtf(var + 1e-5f);
  }
  __syncthreads();
  float mu = stats[0], rstd = stats[1];
  float4 g  = *(const float4*)(gamma + t * 4);
  float4 bt = *(const float4*)(beta + t * 4);
  float4 o;
  o.x = (v.x - mu) * rstd * g.x + bt.x;
  o.y = (v.y - mu) * rstd * g.y + bt.y;
  o.z = (v.z - mu) * rstd * g.z + bt.z;
  o.w = (v.w - mu) * rstd * g.w + bt.w;
  *(float4*)(out + (size_t)row * H_DIM + t * 4) = o;
}

// ---------------- fp32 tiled GEMM: C = A[M,K] @ B[K,N] (+bias, +act, +resid) ----------------
// act: 0 = none, 1 = softplus.  Explicit lda/ldb/ldc (resid uses ldc).
#define GBM 128
#define GBN 128
#define GBK 16

__global__ __launch_bounds__(256) void gemm128(const float* __restrict__ A,
    const float* __restrict__ B, float* __restrict__ C, int K,
    int lda, int ldb, int ldc,
    const float* __restrict__ bias, const float* __restrict__ resid, int act) {
  __shared__ float As[GBK][GBM];
  __shared__ float Bs[GBK][GBN];
  int t = threadIdx.x;
  int m0 = blockIdx.y * GBM, n0 = blockIdx.x * GBN;
  int ty = t >> 4, tx = t & 15;
  float acc[8][8] = {};
  int arow = t >> 1, acol = (t & 1) * 8;
  int brow = t >> 4, bcol = (t & 15) * 8;
  const float* Ap = A + (size_t)(m0 + arow) * lda + acol;
  const float* Bp = B + (size_t)brow * ldb + n0 + bcol;

  for (int k0 = 0; k0 < K; k0 += GBK) {
    float4 a0 = *(const float4*)(Ap + k0);
    float4 a1 = *(const float4*)(Ap + k0 + 4);
    float4 b0 = *(const float4*)(Bp + (size_t)k0 * ldb);
    float4 b1 = *(const float4*)(Bp + (size_t)k0 * ldb + 4);
    __syncthreads();
    As[acol + 0][arow] = a0.x; As[acol + 1][arow] = a0.y;
    As[acol + 2][arow] = a0.z; As[acol + 3][arow] = a0.w;
    As[acol + 4][arow] = a1.x; As[acol + 5][arow] = a1.y;
    As[acol + 6][arow] = a1.z; As[acol + 7][arow] = a1.w;
    *(float4*)&Bs[brow][bcol] = b0;
    *(float4*)&Bs[brow][bcol + 4] = b1;
    __syncthreads();
#pragma unroll
    for (int k = 0; k < GBK; ++k) {
      float4 va0 = *(const float4*)&As[k][ty * 8];
      float4 va1 = *(const float4*)&As[k][ty * 8 + 4];
      float4 vb0 = *(const float4*)&Bs[k][tx * 8];
      float4 vb1 = *(const float4*)&Bs[k][tx * 8 + 4];
      float av[8] = {va0.x, va0.y, va0.z, va0.w, va1.x, va1.y, va1.z, va1.w};
      float bv[8] = {vb0.x, vb0.y, vb0.z, vb0.w, vb1.x, vb1.y, vb1.z, vb1.w};
#pragma unroll
      for (int i = 0; i < 8; ++i)
#pragma unroll
        for (int j = 0; j < 8; ++j)
          acc[i][j] += av[i] * bv[j];
    }
  }

#pragma unroll
  for (int i = 0; i < 8; ++i) {
    int row = m0 + ty * 8 + i;
#pragma unroll
    for (int jj = 0; jj < 2; ++jj) {
      int col = n0 + tx * 8 + jj * 4;
      float4 v;
      v.x = acc[i][jj * 4 + 0]; v.y = acc[i][jj * 4 + 1];
      v.z = acc[i][jj * 4 + 2]; v.w = acc[i][jj * 4 + 3];
      if (bias) {
        float4 bb = *(const float4*)(bias + col);
        v.x += bb.x; v.y += bb.y; v.z += bb.z; v.w += bb.w;
      }
      if (act == 1) {
        v.x = softplusf_(v.x); v.y = softplusf_(v.y);
        v.z = softplusf_(v.z); v.w = softplusf_(v.w);
      }
      if (resid) {
        float4 r = *(const float4*)(resid + (size_t)row * ldc + col);
        v.x += r.x; v.y += r.y; v.z += r.z; v.w += r.w;
      }
      *(float4*)(C + (size_t)row * ldc + col) = v;
    }
  }
}

// ---------------- depthwise conv(3) + SiLU : xb [tok, D] contiguous ----------------
__global__ __launch_bounds__(256) void conv_silu_kernel(const float* __restrict__ xb,
    const float* __restrict__ cw, const float* __restrict__ cb,
    float* __restrict__ xbc) {
  size_t i = (size_t)blockIdx.x * 256 + threadIdx.x;  // < TOKENS*D_DIM
  int d = (int)(i & (D_DIM - 1));
  size_t tok = i >> 11;
  int l = (int)(tok & (L_DIM - 1));
  const float* base = xb + i;
  float w0 = cw[d * 3], w1 = cw[d * 3 + 1], w2 = cw[d * 3 + 2];
  float v = w1 * base[0] + cb[d];
  if (l > 0)         v += w0 * base[-D_DIM];
  if (l < L_DIM - 1) v += w2 * base[ D_DIM];
  v = v * sigmoidf_(v);
  xbc[i] = v;
}

// ---------------- B/C projections: one block per token row ----------------
__global__ __launch_bounds__(256) void bc_kernel(const float* __restrict__ xbc,
    const float* __restrict__ WB, const float* __restrict__ WC,
    float* __restrict__ Bi, float* __restrict__ Ci) {
  __shared__ float sA[D_DIM];
  __shared__ float red[8][32];
  int m = blockIdx.x;
  const float* a = xbc + (size_t)m * D_DIM;
  for (int i = threadIdx.x * 4; i < D_DIM; i += 1024)
    *(float4*)&sA[i] = *(const float4*)&a[i];
  __syncthreads();
  int col = threadIdx.x & 31, slice = threadIdx.x >> 5;
  const float* W = (col < 16) ? WB : WC;
  int c = col & 15;
  float s = 0.f;
  int k0 = slice * 256;
  for (int k = 0; k < 256; ++k) s += sA[k0 + k] * W[(k0 + k) * N_STATE + c];
  red[slice][col] = s;
  __syncthreads();
  if (threadIdx.x < 32) {
    float tsum = 0.f;
#pragma unroll
    for (int i = 0; i < 8; ++i) tsum += red[i][col];
    if (col < 16) Bi[(size_t)m * N_STATE + col] = tsum;
    else          Ci[(size_t)m * N_STATE + (col - 16)] = tsum;
  }
}

// ---------------- selective scan: one lane per (b,d,n) ----------------
// NOTE: y may alias dt (in-wave: step-(l+1) prefetch loads issue before the
// step-l store in lockstep order, and each (b,d) column is owned by exactly
// the 16 lanes doing that store). No __restrict__ on dt/y for that reason.
__global__ __launch_bounds__(256) void scan_kernel(const float* dt,
    const float* __restrict__ xbc, const float* __restrict__ Bi,
    const float* __restrict__ Ci, const float* __restrict__ A_log,
    float* y) {
  int tid = blockIdx.x * 256 + threadIdx.x;   // < B*D*N = 131072
  int n = tid & 15;
  int d = (tid >> 4) & (D_DIM - 1);
  int b = tid >> 15;
  float Aneg = -__expf(A_log[d * N_STATE + n]);
  size_t tok0 = (size_t)b * L_DIM;
  const float* dtp = dt  + tok0 * D_DIM + d;
  const float* xp  = xbc + tok0 * D_DIM + d;
  const float* Bp  = Bi + tok0 * N_STATE + n;
  const float* Cp  = Ci + tok0 * N_STATE + n;
  float* yp = y + tok0 * D_DIM + d;

  float h = 0.f;
  float dtv = dtp[0], xv = xp[0], Bv = Bp[0], Cv = Cp[0];
  for (int l = 0; l < L_DIM; ++l) {
    float dt2 = 0.f, x2 = 0.f, B2 = 0.f, C2 = 0.f;
    if (l < L_DIM - 1) {   // prefetch next step off the h critical path
      dt2 = dtp[(size_t)(l + 1) * D_DIM];
      x2  = xp[(size_t)(l + 1) * D_DIM];
      B2  = Bp[(size_t)(l + 1) * N_STATE];
      C2  = Cp[(size_t)(l + 1) * N_STATE];
    }
    float ab = __expf(dtv * Aneg);
    h = ab * h + (dtv * xv) * Bv;
    float part = h * Cv;
    part += __shfl_xor(part, 1, 16);
    part += __shfl_xor(part, 2, 16);
    part += __shfl_xor(part, 4, 16);
    part += __shfl_xor(part, 8, 16);
    if (n == 0) yp[(size_t)l * D_DIM] = part;
    dtv = dt2; xv = x2; Bv = B2; Cv = C2;
  }
}

// ---------------- gate: y = (y + D*xbc) * silu(z) (in place over y) ----------------
__global__ __launch_bounds__(256) void yf_kernel(float* __restrict__ y,
    const float* __restrict__ xbc, const float* __restrict__ z,
    const float* __restrict__ Dp) {
  size_t i = (size_t)blockIdx.x * 256 + threadIdx.x;
  int d = (int)(i & (D_DIM - 1));
  float zv = z[i];
  float v = (y[i] + Dp[d] * xbc[i]) * (zv * sigmoidf_(zv));
  y[i] = v;
}

extern "C" void kernel_launch(void* const* d_in, const int* in_sizes, int n_in,
                              void* d_out, int out_size, void* d_ws, size_t ws_size,
                              hipStream_t stream) {
  const float* x          = (const float*)d_in[0];
  const float* norm_scale = (const float*)d_in[1];
  const float* norm_bias  = (const float*)d_in[2];
  const float* W_in       = (const float*)d_in[3];
  const float* conv_w     = (const float*)d_in[4];
  const float* conv_b     = (const float*)d_in[5];
  const float* W_dt       = (const float*)d_in[6];
  const float* b_dt       = (const float*)d_in[7];
  const float* A_log      = (const float*)d_in[8];
  const float* D_param    = (const float*)d_in[9];
  const float* W_B        = (const float*)d_in[10];
  const float* W_C        = (const float*)d_in[11];
  const float* W_out      = (const float*)d_in[12];
  float* out = (float*)d_out;

  // Workspace layout (peak 193 MB), liveness-aliased:
  //   [0,       64M)  xb   (GEMM1a -> conv), then dt (GEMM2 -> scan), then y (scan -> GEMM3)
  //   [64M,    128M)  z    (GEMM1b -> gate)
  //   [128M,   192M)  xbc  (conv -> GEMM2/bc/scan/gate)
  //   [192M, +1M)     Bi, Ci
  const size_t SEG = 67108864;              // 64 MB
  const size_t NEEDED = 3 * SEG + 2 * (size_t)TOKENS * N_STATE * 4;
  if (ws_size < NEEDED) return;             // diagnostic bail: ws too small

  char* ws = (char*)d_ws;
  float* xb  = (float*)(ws);
  float* dtY = (float*)(ws);                // aliases xb (dead after conv)
  float* z   = (float*)(ws + SEG);
  float* xbc = (float*)(ws + 2 * SEG);
  float* Bi  = (float*)(ws + 3 * SEG);
  float* Ci  = Bi + (size_t)TOKENS * N_STATE;
  float* xn  = out;  // d_out doubles as xn scratch; final GEMM overwrites it

  // 1. LayerNorm
  ln_kernel<<<TOKENS, 256, 0, stream>>>(x, norm_scale, norm_bias, xn);
  // 2a. xb = xn @ W_in[:, :2048]
  gemm128<<<dim3(D_DIM / GBN, TOKENS / GBM), 256, 0, stream>>>(
      xn, W_in, xb, H_DIM, H_DIM, 2 * D_DIM, D_DIM, nullptr, nullptr, 0);
  // 2b. z = xn @ W_in[:, 2048:]
  gemm128<<<dim3(D_DIM / GBN, TOKENS / GBM), 256, 0, stream>>>(
      xn, W_in + D_DIM, z, H_DIM, H_DIM, 2 * D_DIM, D_DIM, nullptr, nullptr, 0);
  // 3. depthwise conv + silu -> xbc
  conv_silu_kernel<<<(TOKENS * D_DIM) / 256, 256, 0, stream>>>(xb, conv_w, conv_b, xbc);
  // 4. dt = softplus(xbc @ W_dt + b_dt)  (overwrites xb region)
  gemm128<<<dim3(D_DIM / GBN, TOKENS / GBM), 256, 0, stream>>>(
      xbc, W_dt, dtY, D_DIM, D_DIM, D_DIM, D_DIM, b_dt, nullptr, 1);
  // 5. Bi/Ci projections
  bc_kernel<<<TOKENS, 256, 0, stream>>>(xbc, W_B, W_C, Bi, Ci);
  // 6. selective scan -> y (in place over dt)
  scan_kernel<<<(B_DIM * D_DIM * N_STATE) / 256, 256, 0, stream>>>(
      dtY, xbc, Bi, Ci, A_log, dtY);
  // 7. gate (in place over y)
  yf_kernel<<<(TOKENS * D_DIM) / 256, 256, 0, stream>>>(dtY, xbc, z, D_param);
  // 8. out = x + y @ W_out
  gemm128<<<dim3(H_DIM / GBN, TOKENS / GBM), 256, 0, stream>>>(
      dtY, W_out, out, D_DIM, D_DIM, H_DIM, H_DIM, nullptr, x, 0);
}

// Round 3
// 1302.496 us; speedup vs baseline: 2.2304x; 2.2304x over previous
//
#include <hip/hip_runtime.h>
#include <hip/hip_bf16.h>
#include <cstdint>
#include <cstddef>

#define B_DIM 4
#define L_DIM 2048
#define H_DIM 1024
#define D_DIM 2048
#define N_STATE 16
#define TOKENS (B_DIM * L_DIM)   // 8192

typedef __bf16 bf16x8 __attribute__((ext_vector_type(8)));
typedef float f32x4 __attribute__((ext_vector_type(4)));

__device__ __forceinline__ float sigmoidf_(float x) { return 1.f / (1.f + __expf(-x)); }
__device__ __forceinline__ float softplusf_(float x) {
  return fmaxf(x, 0.f) + log1pf(__expf(-fabsf(x)));
}
__device__ __forceinline__ void gl_lds16(const void* g, void* l) {
  __builtin_amdgcn_global_load_lds(
      (const __attribute__((address_space(1))) unsigned int*)g,
      (__attribute__((address_space(3))) unsigned int*)l, 16, 0, 0);
}

// ---------------- LayerNorm -> bf16: one block per token ----------------
__global__ __launch_bounds__(256) void ln_kernel(const float* __restrict__ x,
    const float* __restrict__ gamma, const float* __restrict__ beta,
    __hip_bfloat16* __restrict__ out) {
  int row = blockIdx.x;
  int t = threadIdx.x;
  const float* px = x + (size_t)row * H_DIM;
  float4 v = *(const float4*)(px + t * 4);
  float s  = v.x + v.y + v.z + v.w;
  float ss = v.x * v.x + v.y * v.y + v.z * v.z + v.w * v.w;
  for (int off = 32; off > 0; off >>= 1) {
    s  += __shfl_down(s, off);
    ss += __shfl_down(ss, off);
  }
  __shared__ float red[8];
  __shared__ float stats[2];
  int wave = t >> 6, lane = t & 63;
  if (lane == 0) { red[wave] = s; red[4 + wave] = ss; }
  __syncthreads();
  if (t == 0) {
    float S  = red[0] + red[1] + red[2] + red[3];
    float SS = red[4] + red[5] + red[6] + red[7];
    float mu = S / H_DIM;
    float var = SS / H_DIM - mu * mu;
    stats[0] = mu;
    stats[1] = rsqrtf(var + 1e-5f);
  }
  __syncthreads();
  float mu = stats[0], rstd = stats[1];
  float4 g  = *(const float4*)(gamma + t * 4);
  float4 bt = *(const float4*)(beta + t * 4);
  __hip_bfloat16* po = out + (size_t)row * H_DIM + t * 4;
  po[0] = __float2bfloat16((v.x - mu) * rstd * g.x + bt.x);
  po[1] = __float2bfloat16((v.y - mu) * rstd * g.y + bt.y);
  po[2] = __float2bfloat16((v.z - mu) * rstd * g.z + bt.z);
  po[3] = __float2bfloat16((v.w - mu) * rstd * g.w + bt.w);
}

// ---------------- transpose+convert: in fp32 [R][C] -> out bf16 [C][R] ----------------
__global__ void transpose_bf16(const float* __restrict__ in,
                               __hip_bfloat16* __restrict__ out, int R, int C) {
  __shared__ float tile[32][33];
  int c0 = blockIdx.x * 32, r0 = blockIdx.y * 32;
  int tx = threadIdx.x, ty = threadIdx.y;   // (32, 8)
  for (int i = 0; i < 32; i += 8)
    tile[ty + i][tx] = in[(size_t)(r0 + ty + i) * C + c0 + tx];
  __syncthreads();
  for (int i = 0; i < 32; i += 8)
    out[(size_t)(c0 + ty + i) * R + r0 + tx] = __float2bfloat16(tile[tx][ty + i]);
}

// ---------------- bf16 MFMA GEMM (m97 structure): C = A[M,K] @ Bt[N,K]^T ----------------
// 128x128 tile, BK=32, 4 waves each computing 64x64 via 4x4 mfma_f32_16x16x32_bf16.
// act: 1 = softplus. out_bf16: store bf16 else fp32. resid: fp32, indexed with ldc.
#define BM 128
#define BN 128
#define BK 32

__global__ __launch_bounds__(256) void gemm_bf16(
    const __hip_bfloat16* __restrict__ A, const __hip_bfloat16* __restrict__ Bt,
    void* __restrict__ Cout, int K, int lda, int ldb, int ldc,
    const float* __restrict__ bias, const float* __restrict__ resid,
    int act, int out_bf16) {
  __shared__ __hip_bfloat16 As[BM * BK];
  __shared__ __hip_bfloat16 Bs[BN * BK];
  int t = threadIdx.x;
  int m0 = blockIdx.y * BM, n0 = blockIdx.x * BN;
  int wave = t >> 6, lane = t & 63;
  int quad = lane >> 4, l16 = lane & 15;
  int wm = (wave >> 1) * 64, wn = (wave & 1) * 64;

  f32x4 acc[4][4] = {};

  // staging: thread t -> row t>>2 (0..63), 8-elem chunk (t&3)*8; 2 issues cover 128 rows
  int srow = t >> 2;
  int scol = (t & 3) * 8;
  const __hip_bfloat16* Ag  = A  + (size_t)(m0 + srow) * lda + scol;
  const __hip_bfloat16* Ag2 = Ag + (size_t)64 * lda;
  const __hip_bfloat16* Bg  = Bt + (size_t)(n0 + srow) * ldb + scol;
  const __hip_bfloat16* Bg2 = Bg + (size_t)64 * ldb;
  __hip_bfloat16* Asl  = &As[t * 8];        // contiguous in t: lds = base + lane*16B
  __hip_bfloat16* Asl2 = Asl + 64 * BK;
  __hip_bfloat16* Bsl  = &Bs[t * 8];
  __hip_bfloat16* Bsl2 = Bsl + 64 * BK;

  for (int k0 = 0; k0 < K; k0 += BK) {
    __syncthreads();
    gl_lds16(Ag  + k0, Asl);
    gl_lds16(Ag2 + k0, Asl2);
    gl_lds16(Bg  + k0, Bsl);
    gl_lds16(Bg2 + k0, Bsl2);
    __syncthreads();
    bf16x8 af[4], bf_[4];
#pragma unroll
    for (int i = 0; i < 4; ++i) {
      af[i]  = *(const bf16x8*)&As[(wm + i * 16 + l16) * BK + quad * 8];
      bf_[i] = *(const bf16x8*)&Bs[(wn + i * 16 + l16) * BK + quad * 8];
    }
#pragma unroll
    for (int i = 0; i < 4; ++i)
#pragma unroll
      for (int j = 0; j < 4; ++j)
        acc[i][j] = __builtin_amdgcn_mfma_f32_16x16x32_bf16(af[i], bf_[j], acc[i][j], 0, 0, 0);
  }

  float* Cf = (float*)Cout;
  __hip_bfloat16* Cb = (__hip_bfloat16*)Cout;
#pragma unroll
  for (int i = 0; i < 4; ++i) {
    int row0 = m0 + wm + i * 16 + quad * 4;   // C/D: col=lane&15, row=quad*4+reg
#pragma unroll
    for (int j = 0; j < 4; ++j) {
      int col = n0 + wn + j * 16 + l16;
      f32x4 v = acc[i][j];
      if (bias) {
        float bb = bias[col];
        v[0] += bb; v[1] += bb; v[2] += bb; v[3] += bb;
      }
      if (act == 1) {
        v[0] = softplusf_(v[0]); v[1] = softplusf_(v[1]);
        v[2] = softplusf_(v[2]); v[3] = softplusf_(v[3]);
      }
#pragma unroll
      for (int r = 0; r < 4; ++r) {
        size_t idx = (size_t)(row0 + r) * ldc + col;
        float val = v[r];
        if (resid) val += resid[idx];
        if (out_bf16) Cb[idx] = __float2bfloat16(val);
        else          Cf[idx] = val;
      }
    }
  }
}

// ---------------- depthwise conv(3) + SiLU, bf16 in/out, 2 channels/thread ----------------
__global__ __launch_bounds__(256) void conv_silu_kernel(const __hip_bfloat16* __restrict__ xb,
    const float* __restrict__ cw, const float* __restrict__ cb,
    __hip_bfloat16* __restrict__ xbc) {
  size_t i2 = (size_t)blockIdx.x * 256 + threadIdx.x;  // pair index < TOKENS*D_DIM/2
  int dp = (int)(i2 & (D_DIM / 2 - 1));
  size_t tok = i2 >> 10;
  int l = (int)(tok & (L_DIM - 1));
  int d = dp * 2;
  const __hip_bfloat162* base = (const __hip_bfloat162*)xb + i2;
  __hip_bfloat162 cc = base[0];
  float v0 = cw[d * 3 + 1] * __bfloat162float(cc.x) + cb[d];
  float v1 = cw[d * 3 + 4] * __bfloat162float(cc.y) + cb[d + 1];
  if (l > 0) {
    __hip_bfloat162 pm = base[-(D_DIM / 2)];
    v0 += cw[d * 3 + 0] * __bfloat162float(pm.x);
    v1 += cw[d * 3 + 3] * __bfloat162float(pm.y);
  }
  if (l < L_DIM - 1) {
    __hip_bfloat162 pp = base[D_DIM / 2];
    v0 += cw[d * 3 + 2] * __bfloat162float(pp.x);
    v1 += cw[d * 3 + 5] * __bfloat162float(pp.y);
  }
  v0 = v0 * sigmoidf_(v0);
  v1 = v1 * sigmoidf_(v1);
  __hip_bfloat162 o;
  o.x = __float2bfloat16(v0);
  o.y = __float2bfloat16(v1);
  ((__hip_bfloat162*)xbc)[i2] = o;
}

// ---------------- B/C projections: one block per token row ----------------
__global__ __launch_bounds__(256) void bc_kernel(const __hip_bfloat16* __restrict__ xbc,
    const float* __restrict__ WB, const float* __restrict__ WC,
    float* __restrict__ Bi, float* __restrict__ Ci) {
  __shared__ float sA[D_DIM];
  __shared__ float red[8][32];
  int m = blockIdx.x;
  const __hip_bfloat162* a = (const __hip_bfloat162*)(xbc + (size_t)m * D_DIM);
  for (int i = threadIdx.x; i < D_DIM / 2; i += 256) {
    __hip_bfloat162 p = a[i];
    sA[2 * i]     = __bfloat162float(p.x);
    sA[2 * i + 1] = __bfloat162float(p.y);
  }
  __syncthreads();
  int col = threadIdx.x & 31, slice = threadIdx.x >> 5;
  const float* W = (col < 16) ? WB : WC;
  int c = col & 15;
  float s = 0.f;
  int k0 = slice * 256;
  for (int k = 0; k < 256; ++k) s += sA[k0 + k] * W[(k0 + k) * N_STATE + c];
  red[slice][col] = s;
  __syncthreads();
  if (threadIdx.x < 32) {
    float tsum = 0.f;
#pragma unroll
    for (int i = 0; i < 8; ++i) tsum += red[i][col];
    if (col < 16) Bi[(size_t)m * N_STATE + col] = tsum;
    else          Ci[(size_t)m * N_STATE + (col - 16)] = tsum;
  }
}

// ---------------- selective scan: one lane per (b,d,n) ----------------
// y may alias dt (in-wave: step-(l+1) prefetch loads issue before the step-l
// store in lockstep order; each (b,d) column is owned by the 16 storing lanes).
__global__ __launch_bounds__(256) void scan_kernel(const float* dt,
    const __hip_bfloat16* __restrict__ xbc, const float* __restrict__ Bi,
    const float* __restrict__ Ci, const float* __restrict__ A_log,
    float* y) {
  int tid = blockIdx.x * 256 + threadIdx.x;   // < B*D*N = 131072
  int n = tid & 15;
  int d = (tid >> 4) & (D_DIM - 1);
  int b = tid >> 15;
  float Aneg = -__expf(A_log[d * N_STATE + n]);
  size_t tok0 = (size_t)b * L_DIM;
  const float* dtp = dt + tok0 * D_DIM + d;
  const __hip_bfloat16* xp = xbc + tok0 * D_DIM + d;
  const float* Bp = Bi + tok0 * N_STATE + n;
  const float* Cp = Ci + tok0 * N_STATE + n;
  float* yp = y + tok0 * D_DIM + d;

  float h = 0.f;
  float dtv = dtp[0], xv = __bfloat162float(xp[0]), Bv = Bp[0], Cv = Cp[0];
  for (int l = 0; l < L_DIM; ++l) {
    float dt2 = 0.f, x2 = 0.f, B2 = 0.f, C2 = 0.f;
    if (l < L_DIM - 1) {   // prefetch next step off the h critical path
      dt2 = dtp[(size_t)(l + 1) * D_DIM];
      x2  = __bfloat162float(xp[(size_t)(l + 1) * D_DIM]);
      B2  = Bp[(size_t)(l + 1) * N_STATE];
      C2  = Cp[(size_t)(l + 1) * N_STATE];
    }
    float ab = __expf(dtv * Aneg);
    h = ab * h + (dtv * xv) * Bv;
    float part = h * Cv;
    part += __shfl_xor(part, 1, 16);
    part += __shfl_xor(part, 2, 16);
    part += __shfl_xor(part, 4, 16);
    part += __shfl_xor(part, 8, 16);
    if (n == 0) yp[(size_t)l * D_DIM] = part;
    dtv = dt2; xv = x2; Bv = B2; Cv = C2;
  }
}

// ---------------- gate: yo_bf16 = (y + D*xbc) * silu(z) ----------------
__global__ __launch_bounds__(256) void yf_kernel(const float* __restrict__ y,
    const __hip_bfloat16* __restrict__ xbc, const __hip_bfloat16* __restrict__ z,
    const float* __restrict__ Dp, __hip_bfloat16* __restrict__ yo) {
  size_t i = (size_t)blockIdx.x * 256 + threadIdx.x;
  int d = (int)(i & (D_DIM - 1));
  float zv = __bfloat162float(z[i]);
  float v = (y[i] + Dp[d] * __bfloat162float(xbc[i])) * (zv * sigmoidf_(zv));
  yo[i] = __float2bfloat16(v);
}

extern "C" void kernel_launch(void* const* d_in, const int* in_sizes, int n_in,
                              void* d_out, int out_size, void* d_ws, size_t ws_size,
                              hipStream_t stream) {
  const float* x          = (const float*)d_in[0];
  const float* norm_scale = (const float*)d_in[1];
  const float* norm_bias  = (const float*)d_in[2];
  const float* W_in       = (const float*)d_in[3];
  const float* conv_w     = (const float*)d_in[4];
  const float* conv_b     = (const float*)d_in[5];
  const float* W_dt       = (const float*)d_in[6];
  const float* b_dt       = (const float*)d_in[7];
  const float* A_log      = (const float*)d_in[8];
  const float* D_param    = (const float*)d_in[9];
  const float* W_B        = (const float*)d_in[10];
  const float* W_C        = (const float*)d_in[11];
  const float* W_out      = (const float*)d_in[12];
  float* out = (float*)d_out;

  // Workspace layout (193 MB, identical footprint to the passing R2 layout):
  //  S0 [  0, 16M): xn bf16 (LN->GEMM1b), then W_outT bf16 (4MB, conv->GEMM3)
  //  S1 [ 16, 48M): xb bf16 (GEMM1a->conv), then y bf16 (gate->GEMM3)
  //  S2 [ 48, 80M): z bf16 (GEMM1b->gate)
  //  S3 [ 80,112M): xbc bf16 (conv->gate)
  //  S4 [112,176M): dt fp32 (GEMM2->scan, scan writes y in place ->gate)
  //  S5 [176,177M): Bi, Ci fp32
  //  S6 [177,185M): W_inT bf16 [4096][1024]
  //  S7 [185,193M): W_dtT bf16 [2048][2048]
  const size_t MB = 1024 * 1024;
  const size_t NEEDED = 193 * MB;
  if (ws_size < NEEDED) return;   // diagnostic bail: ws too small

  char* ws = (char*)d_ws;
  __hip_bfloat16* xn     = (__hip_bfloat16*)(ws);
  __hip_bfloat16* W_outT = (__hip_bfloat16*)(ws);            // after GEMM1b
  __hip_bfloat16* xb     = (__hip_bfloat16*)(ws + 16 * MB);
  __hip_bfloat16* ybf    = (__hip_bfloat16*)(ws + 16 * MB);  // after conv
  __hip_bfloat16* z      = (__hip_bfloat16*)(ws + 48 * MB);
  __hip_bfloat16* xbc    = (__hip_bfloat16*)(ws + 80 * MB);
  float*          dtY    = (float*)(ws + 112 * MB);
  float*          Bi     = (float*)(ws + 176 * MB);
  float*          Ci     = Bi + (size_t)TOKENS * N_STATE;
  __hip_bfloat16* W_inT  = (__hip_bfloat16*)(ws + 177 * MB);
  __hip_bfloat16* W_dtT  = (__hip_bfloat16*)(ws + 185 * MB);

  dim3 tb(32, 8);
  // 0. weight transpose+convert (W_out's goes later, into S0)
  transpose_bf16<<<dim3(4096 / 32, 1024 / 32), tb, 0, stream>>>(W_in, W_inT, 1024, 4096);
  transpose_bf16<<<dim3(2048 / 32, 2048 / 32), tb, 0, stream>>>(W_dt, W_dtT, 2048, 2048);
  // 1. LayerNorm -> bf16
  ln_kernel<<<TOKENS, 256, 0, stream>>>(x, norm_scale, norm_bias, xn);
  // 2a. xb = xn @ W_in[:, :2048]        (bf16 out)
  gemm_bf16<<<dim3(D_DIM / BN, TOKENS / BM), 256, 0, stream>>>(
      xn, W_inT, xb, H_DIM, H_DIM, H_DIM, D_DIM, nullptr, nullptr, 0, 1);
  // 2b. z = xn @ W_in[:, 2048:]        (bf16 out)
  gemm_bf16<<<dim3(D_DIM / BN, TOKENS / BM), 256, 0, stream>>>(
      xn, W_inT + (size_t)D_DIM * H_DIM, z, H_DIM, H_DIM, H_DIM, D_DIM,
      nullptr, nullptr, 0, 1);
  // (xn dead) convert W_out into S0
  transpose_bf16<<<dim3(1024 / 32, 2048 / 32), tb, 0, stream>>>(W_out, W_outT, 2048, 1024);
  // 3. depthwise conv + silu -> xbc bf16
  conv_silu_kernel<<<(TOKENS * D_DIM / 2) / 256, 256, 0, stream>>>(xb, conv_w, conv_b, xbc);
  // 4. dt = softplus(xbc @ W_dt + b_dt) -> fp32
  gemm_bf16<<<dim3(D_DIM / BN, TOKENS / BM), 256, 0, stream>>>(
      xbc, W_dtT, dtY, D_DIM, D_DIM, D_DIM, D_DIM, b_dt, nullptr, 1, 0);
  // 5. Bi/Ci projections
  bc_kernel<<<TOKENS, 256, 0, stream>>>(xbc, W_B, W_C, Bi, Ci);
  // 6. selective scan -> y fp32 (in place over dt)
  scan_kernel<<<(B_DIM * D_DIM * N_STATE) / 256, 256, 0, stream>>>(
      dtY, xbc, Bi, Ci, A_log, dtY);
  // 7. gate -> y bf16 (into S1; xb dead)
  yf_kernel<<<(TOKENS * D_DIM) / 256, 256, 0, stream>>>(dtY, xbc, z, D_param, ybf);
  // 8. out = x + y @ W_out   (fp32 out + residual)
  gemm_bf16<<<dim3(H_DIM / BN, TOKENS / BM), 256, 0, stream>>>(
      ybf, W_outT, out, D_DIM, D_DIM, D_DIM, H_DIM, nullptr, x, 0, 0);
}

// Round 4
// 1125.011 us; speedup vs baseline: 2.5823x; 1.1578x over previous
//
#include <hip/hip_runtime.h>
#include <hip/hip_bf16.h>
#include <cstdint>
#include <cstddef>

#define B_DIM 4
#define L_DIM 2048
#define H_DIM 1024
#define D_DIM 2048
#define N_STATE 16
#define TOKENS (B_DIM * L_DIM)   // 8192
#define CH 16                    // scan chunks
#define LC (L_DIM / CH)          // 128 steps per chunk

typedef __bf16 bf16x8 __attribute__((ext_vector_type(8)));
typedef float f32x4 __attribute__((ext_vector_type(4)));

__device__ __forceinline__ float sigmoidf_(float x) { return 1.f / (1.f + __expf(-x)); }
__device__ __forceinline__ float softplusf_(float x) {
  return fmaxf(x, 0.f) + log1pf(__expf(-fabsf(x)));
}
__device__ __forceinline__ void gl_lds16(const void* g, void* l) {
  __builtin_amdgcn_global_load_lds(
      (const __attribute__((address_space(1))) unsigned int*)g,
      (__attribute__((address_space(3))) unsigned int*)l, 16, 0, 0);
}

// ---------------- LayerNorm -> bf16: one block per token ----------------
__global__ __launch_bounds__(256) void ln_kernel(const float* __restrict__ x,
    const float* __restrict__ gamma, const float* __restrict__ beta,
    __hip_bfloat16* __restrict__ out) {
  int row = blockIdx.x;
  int t = threadIdx.x;
  const float* px = x + (size_t)row * H_DIM;
  float4 v = *(const float4*)(px + t * 4);
  float s  = v.x + v.y + v.z + v.w;
  float ss = v.x * v.x + v.y * v.y + v.z * v.z + v.w * v.w;
  for (int off = 32; off > 0; off >>= 1) {
    s  += __shfl_down(s, off);
    ss += __shfl_down(ss, off);
  }
  __shared__ float red[8];
  __shared__ float stats[2];
  int wave = t >> 6, lane = t & 63;
  if (lane == 0) { red[wave] = s; red[4 + wave] = ss; }
  __syncthreads();
  if (t == 0) {
    float S  = red[0] + red[1] + red[2] + red[3];
    float SS = red[4] + red[5] + red[6] + red[7];
    float mu = S / H_DIM;
    float var = SS / H_DIM - mu * mu;
    stats[0] = mu;
    stats[1] = rsqrtf(var + 1e-5f);
  }
  __syncthreads();
  float mu = stats[0], rstd = stats[1];
  float4 g  = *(const float4*)(gamma + t * 4);
  float4 bt = *(const float4*)(beta + t * 4);
  __hip_bfloat16* po = out + (size_t)row * H_DIM + t * 4;
  po[0] = __float2bfloat16((v.x - mu) * rstd * g.x + bt.x);
  po[1] = __float2bfloat16((v.y - mu) * rstd * g.y + bt.y);
  po[2] = __float2bfloat16((v.z - mu) * rstd * g.z + bt.z);
  po[3] = __float2bfloat16((v.w - mu) * rstd * g.w + bt.w);
}

// ---------------- transpose+convert: in fp32 [R][C] -> out bf16 [C][R] ----------------
__global__ void transpose_bf16(const float* __restrict__ in,
                               __hip_bfloat16* __restrict__ out, int R, int C) {
  __shared__ float tile[32][33];
  int c0 = blockIdx.x * 32, r0 = blockIdx.y * 32;
  int tx = threadIdx.x, ty = threadIdx.y;   // (32, 8)
  for (int i = 0; i < 32; i += 8)
    tile[ty + i][tx] = in[(size_t)(r0 + ty + i) * C + c0 + tx];
  __syncthreads();
  for (int i = 0; i < 32; i += 8)
    out[(size_t)(c0 + ty + i) * R + r0 + tx] = __float2bfloat16(tile[tx][ty + i]);
}

// ---------------- bf16 MFMA GEMM (m97 structure): C = A[M,K] @ Bt[N,K]^T ----------------
#define BM 128
#define BN 128
#define BK 32

__global__ __launch_bounds__(256) void gemm_bf16(
    const __hip_bfloat16* __restrict__ A, const __hip_bfloat16* __restrict__ Bt,
    void* __restrict__ Cout, int K, int lda, int ldb, int ldc,
    const float* __restrict__ bias, const float* __restrict__ resid,
    int act, int out_bf16) {
  __shared__ __hip_bfloat16 As[BM * BK];
  __shared__ __hip_bfloat16 Bs[BN * BK];
  int t = threadIdx.x;
  int m0 = blockIdx.y * BM, n0 = blockIdx.x * BN;
  int wave = t >> 6, lane = t & 63;
  int quad = lane >> 4, l16 = lane & 15;
  int wm = (wave >> 1) * 64, wn = (wave & 1) * 64;

  f32x4 acc[4][4] = {};

  int srow = t >> 2;
  int scol = (t & 3) * 8;
  const __hip_bfloat16* Ag  = A  + (size_t)(m0 + srow) * lda + scol;
  const __hip_bfloat16* Ag2 = Ag + (size_t)64 * lda;
  const __hip_bfloat16* Bg  = Bt + (size_t)(n0 + srow) * ldb + scol;
  const __hip_bfloat16* Bg2 = Bg + (size_t)64 * ldb;
  __hip_bfloat16* Asl  = &As[t * 8];
  __hip_bfloat16* Asl2 = Asl + 64 * BK;
  __hip_bfloat16* Bsl  = &Bs[t * 8];
  __hip_bfloat16* Bsl2 = Bsl + 64 * BK;

  for (int k0 = 0; k0 < K; k0 += BK) {
    __syncthreads();
    gl_lds16(Ag  + k0, Asl);
    gl_lds16(Ag2 + k0, Asl2);
    gl_lds16(Bg  + k0, Bsl);
    gl_lds16(Bg2 + k0, Bsl2);
    __syncthreads();
    bf16x8 af[4], bf_[4];
#pragma unroll
    for (int i = 0; i < 4; ++i) {
      af[i]  = *(const bf16x8*)&As[(wm + i * 16 + l16) * BK + quad * 8];
      bf_[i] = *(const bf16x8*)&Bs[(wn + i * 16 + l16) * BK + quad * 8];
    }
#pragma unroll
    for (int i = 0; i < 4; ++i)
#pragma unroll
      for (int j = 0; j < 4; ++j)
        acc[i][j] = __builtin_amdgcn_mfma_f32_16x16x32_bf16(af[i], bf_[j], acc[i][j], 0, 0, 0);
  }

  float* Cf = (float*)Cout;
  __hip_bfloat16* Cb = (__hip_bfloat16*)Cout;
#pragma unroll
  for (int i = 0; i < 4; ++i) {
    int row0 = m0 + wm + i * 16 + quad * 4;   // C/D: col=lane&15, row=quad*4+reg
#pragma unroll
    for (int j = 0; j < 4; ++j) {
      int col = n0 + wn + j * 16 + l16;
      f32x4 v = acc[i][j];
      if (bias) {
        float bb = bias[col];
        v[0] += bb; v[1] += bb; v[2] += bb; v[3] += bb;
      }
      if (act == 1) {
        v[0] = softplusf_(v[0]); v[1] = softplusf_(v[1]);
        v[2] = softplusf_(v[2]); v[3] = softplusf_(v[3]);
      }
#pragma unroll
      for (int r = 0; r < 4; ++r) {
        size_t idx = (size_t)(row0 + r) * ldc + col;
        float val = v[r];
        if (resid) val += resid[idx];
        if (out_bf16) Cb[idx] = __float2bfloat16(val);
        else          Cf[idx] = val;
      }
    }
  }
}

// ---------------- depthwise conv(3) + SiLU, bf16 in/out ----------------
__global__ __launch_bounds__(256) void conv_silu_kernel(const __hip_bfloat16* __restrict__ xb,
    const float* __restrict__ cw, const float* __restrict__ cb,
    __hip_bfloat16* __restrict__ xbc) {
  size_t i2 = (size_t)blockIdx.x * 256 + threadIdx.x;  // pair index < TOKENS*D_DIM/2
  int dp = (int)(i2 & (D_DIM / 2 - 1));
  size_t tok = i2 >> 10;
  int l = (int)(tok & (L_DIM - 1));
  int d = dp * 2;
  const __hip_bfloat162* base = (const __hip_bfloat162*)xb + i2;
  __hip_bfloat162 cc = base[0];
  float v0 = cw[d * 3 + 1] * __bfloat162float(cc.x) + cb[d];
  float v1 = cw[d * 3 + 4] * __bfloat162float(cc.y) + cb[d + 1];
  if (l > 0) {
    __hip_bfloat162 pm = base[-(D_DIM / 2)];
    v0 += cw[d * 3 + 0] * __bfloat162float(pm.x);
    v1 += cw[d * 3 + 3] * __bfloat162float(pm.y);
  }
  if (l < L_DIM - 1) {
    __hip_bfloat162 pp = base[D_DIM / 2];
    v0 += cw[d * 3 + 2] * __bfloat162float(pp.x);
    v1 += cw[d * 3 + 5] * __bfloat162float(pp.y);
  }
  v0 = v0 * sigmoidf_(v0);
  v1 = v1 * sigmoidf_(v1);
  __hip_bfloat162 o;
  o.x = __float2bfloat16(v0);
  o.y = __float2bfloat16(v1);
  ((__hip_bfloat162*)xbc)[i2] = o;
}

// ---------------- B/C projections: one block per token row ----------------
__global__ __launch_bounds__(256) void bc_kernel(const __hip_bfloat16* __restrict__ xbc,
    const float* __restrict__ WB, const float* __restrict__ WC,
    float* __restrict__ Bi, float* __restrict__ Ci) {
  __shared__ float sA[D_DIM];
  __shared__ float red[8][32];
  int m = blockIdx.x;
  const __hip_bfloat162* a = (const __hip_bfloat162*)(xbc + (size_t)m * D_DIM);
  for (int i = threadIdx.x; i < D_DIM / 2; i += 256) {
    __hip_bfloat162 p = a[i];
    sA[2 * i]     = __bfloat162float(p.x);
    sA[2 * i + 1] = __bfloat162float(p.y);
  }
  __syncthreads();
  int col = threadIdx.x & 31, slice = threadIdx.x >> 5;
  const float* W = (col < 16) ? WB : WC;
  int c = col & 15;
  float s = 0.f;
  int k0 = slice * 256;
  for (int k = 0; k < 256; ++k) s += sA[k0 + k] * W[(k0 + k) * N_STATE + c];
  red[slice][col] = s;
  __syncthreads();
  if (threadIdx.x < 32) {
    float tsum = 0.f;
#pragma unroll
    for (int i = 0; i < 8; ++i) tsum += red[i][col];
    if (col < 16) Bi[(size_t)m * N_STATE + col] = tsum;
    else          Ci[(size_t)m * N_STATE + (col - 16)] = tsum;
  }
}

// ---------------- chunked scan phase 1: local scan per (b,chunk,d,n) ----------------
// block = 16 d x 16 n; grid = (D/16, CH, B)
__global__ __launch_bounds__(256) void scan1_kernel(const float* __restrict__ dt,
    const __hip_bfloat16* __restrict__ xbc, const float* __restrict__ Bi,
    const float* __restrict__ A_log, float* __restrict__ hfin,
    float* __restrict__ dtsum) {
  int n = threadIdx.x & 15;
  int d = blockIdx.x * 16 + ((threadIdx.x >> 4) & 15);
  int c = blockIdx.y;
  int b = blockIdx.z;
  float Aneg = -__expf(A_log[d * N_STATE + n]);
  size_t base = (size_t)b * L_DIM + (size_t)c * LC;
  const float* dtp = dt + base * D_DIM + d;
  const __hip_bfloat16* xp = xbc + base * D_DIM + d;
  const float* Bp = Bi + base * N_STATE + n;
  float h = 0.f, ds = 0.f;
  float dtv = dtp[0], xv = __bfloat162float(xp[0]), Bv = Bp[0];
  for (int i = 0; i < LC; ++i) {
    int ip = (i < LC - 1) ? i + 1 : i;    // clamped prefetch (last value unused)
    float dt2 = dtp[(size_t)ip * D_DIM];
    float x2  = __bfloat162float(xp[(size_t)ip * D_DIM]);
    float B2  = Bp[(size_t)ip * N_STATE];
    float a = __expf(dtv * Aneg);
    h = a * h + (dtv * xv) * Bv;
    ds += dtv;
    dtv = dt2; xv = x2; Bv = B2;
  }
  size_t o = (((size_t)b * CH + c) * D_DIM + d) * N_STATE + n;
  hfin[o] = h;
  if (n == 0) dtsum[((size_t)b * CH + c) * D_DIM + d] = ds;
}

// ---------------- chunked scan phase 2: combine across chunks ----------------
__global__ __launch_bounds__(256) void scan2_kernel(const float* __restrict__ hfin,
    const float* __restrict__ dtsum, const float* __restrict__ A_log,
    float* __restrict__ hstart) {
  int tid = blockIdx.x * 256 + threadIdx.x;   // < B*D*N = 131072
  int n = tid & 15;
  int d = (tid >> 4) & (D_DIM - 1);
  int b = tid >> 15;
  float Aneg = -__expf(A_log[d * N_STATE + n]);
  float run = 0.f;
  for (int c = 0; c < CH; ++c) {
    size_t o = (((size_t)b * CH + c) * D_DIM + d) * N_STATE + n;
    hstart[o] = run;
    run = __expf(Aneg * dtsum[((size_t)b * CH + c) * D_DIM + d]) * run + hfin[o];
  }
}

// ---------------- chunked scan phase 3: rescan with hstart + fused gate ----------------
__global__ __launch_bounds__(256) void scan3_kernel(const float* __restrict__ dt,
    const __hip_bfloat16* __restrict__ xbc, const float* __restrict__ Bi,
    const float* __restrict__ Ci, const float* __restrict__ A_log,
    const float* __restrict__ hstart, const __hip_bfloat16* __restrict__ z,
    const float* __restrict__ Dp, __hip_bfloat16* __restrict__ yo) {
  int n = threadIdx.x & 15;
  int d = blockIdx.x * 16 + ((threadIdx.x >> 4) & 15);
  int c = blockIdx.y;
  int b = blockIdx.z;
  float Aneg = -__expf(A_log[d * N_STATE + n]);
  float Dv = Dp[d];
  size_t base = (size_t)b * L_DIM + (size_t)c * LC;
  const float* dtp = dt + base * D_DIM + d;
  const __hip_bfloat16* xp = xbc + base * D_DIM + d;
  const float* Bp = Bi + base * N_STATE + n;
  const float* Cp = Ci + base * N_STATE + n;
  const __hip_bfloat16* zp = z + base * D_DIM + d;
  __hip_bfloat16* yp = yo + base * D_DIM + d;
  float h = hstart[(((size_t)b * CH + c) * D_DIM + d) * N_STATE + n];
  float dtv = dtp[0], xv = __bfloat162float(xp[0]), Bv = Bp[0], Cv = Cp[0];
  for (int i = 0; i < LC; ++i) {
    int ip = (i < LC - 1) ? i + 1 : i;
    float dt2 = dtp[(size_t)ip * D_DIM];
    float x2  = __bfloat162float(xp[(size_t)ip * D_DIM]);
    float B2  = Bp[(size_t)ip * N_STATE];
    float C2  = Cp[(size_t)ip * N_STATE];
    float a = __expf(dtv * Aneg);
    h = a * h + (dtv * xv) * Bv;
    float part = h * Cv;
    part += __shfl_xor(part, 1, 16);
    part += __shfl_xor(part, 2, 16);
    part += __shfl_xor(part, 4, 16);
    part += __shfl_xor(part, 8, 16);
    if (n == 0) {
      float zv = __bfloat162float(zp[(size_t)i * D_DIM]);
      float v = (part + Dv * xv) * (zv * sigmoidf_(zv));
      yp[(size_t)i * D_DIM] = __float2bfloat16(v);
    }
    dtv = dt2; xv = x2; Bv = B2; Cv = C2;
  }
}

extern "C" void kernel_launch(void* const* d_in, const int* in_sizes, int n_in,
                              void* d_out, int out_size, void* d_ws, size_t ws_size,
                              hipStream_t stream) {
  const float* x          = (const float*)d_in[0];
  const float* norm_scale = (const float*)d_in[1];
  const float* norm_bias  = (const float*)d_in[2];
  const float* W_in       = (const float*)d_in[3];
  const float* conv_w     = (const float*)d_in[4];
  const float* conv_b     = (const float*)d_in[5];
  const float* W_dt       = (const float*)d_in[6];
  const float* b_dt       = (const float*)d_in[7];
  const float* A_log      = (const float*)d_in[8];
  const float* D_param    = (const float*)d_in[9];
  const float* W_B        = (const float*)d_in[10];
  const float* W_C        = (const float*)d_in[11];
  const float* W_out      = (const float*)d_in[12];
  float* out = (float*)d_out;

  // Workspace layout (193 MB, same proven footprint):
  //  S0 [  0, 16M): xn bf16 (8M; dead after GEMM1b) -> W_outT [0,4M),
  //                 hfin fp32 [4,12M), dtsum fp32 [12,12.5M)
  //  S1 [ 16, 48M): xb bf16 (GEMM1a->conv) -> ybf bf16 (scan3 -> GEMM3)
  //  S2 [ 48, 80M): z bf16 (GEMM1b->scan3)
  //  S3 [ 80,112M): xbc bf16 (conv->scan)
  //  S4 [112,176M): dt fp32 (GEMM2->scan)
  //  S5 [176,177M): Bi, Ci fp32
  //  S6 [177,185M): W_inT bf16 (dead after GEMM1b) -> hstart fp32 (8M)
  //  S7 [185,193M): W_dtT bf16
  const size_t MB = 1024 * 1024;
  const size_t NEEDED = 193 * MB;
  if (ws_size < NEEDED) return;   // diagnostic bail: ws too small

  char* ws = (char*)d_ws;
  __hip_bfloat16* xn     = (__hip_bfloat16*)(ws);
  __hip_bfloat16* W_outT = (__hip_bfloat16*)(ws);            // [0,4M) after xn dead
  float*          hfin   = (float*)(ws + 4 * MB);            // [4,12M)
  float*          dtsum  = (float*)(ws + 12 * MB);           // [12,12.5M)
  __hip_bfloat16* xb     = (__hip_bfloat16*)(ws + 16 * MB);
  __hip_bfloat16* ybf    = (__hip_bfloat16*)(ws + 16 * MB);  // after conv
  __hip_bfloat16* z      = (__hip_bfloat16*)(ws + 48 * MB);
  __hip_bfloat16* xbc    = (__hip_bfloat16*)(ws + 80 * MB);
  float*          dtY    = (float*)(ws + 112 * MB);
  float*          Bi     = (float*)(ws + 176 * MB);
  float*          Ci     = Bi + (size_t)TOKENS * N_STATE;
  __hip_bfloat16* W_inT  = (__hip_bfloat16*)(ws + 177 * MB);
  float*          hstart = (float*)(ws + 177 * MB);          // after W_inT dead
  __hip_bfloat16* W_dtT  = (__hip_bfloat16*)(ws + 185 * MB);

  dim3 tb(32, 8);
  // 0. weight transpose+convert
  transpose_bf16<<<dim3(4096 / 32, 1024 / 32), tb, 0, stream>>>(W_in, W_inT, 1024, 4096);
  transpose_bf16<<<dim3(2048 / 32, 2048 / 32), tb, 0, stream>>>(W_dt, W_dtT, 2048, 2048);
  // 1. LayerNorm -> bf16
  ln_kernel<<<TOKENS, 256, 0, stream>>>(x, norm_scale, norm_bias, xn);
  // 2a. xb = xn @ W_in[:, :2048]
  gemm_bf16<<<dim3(D_DIM / BN, TOKENS / BM), 256, 0, stream>>>(
      xn, W_inT, xb, H_DIM, H_DIM, H_DIM, D_DIM, nullptr, nullptr, 0, 1);
  // 2b. z = xn @ W_in[:, 2048:]
  gemm_bf16<<<dim3(D_DIM / BN, TOKENS / BM), 256, 0, stream>>>(
      xn, W_inT + (size_t)D_DIM * H_DIM, z, H_DIM, H_DIM, H_DIM, D_DIM,
      nullptr, nullptr, 0, 1);
  // (xn dead) convert W_out into S0
  transpose_bf16<<<dim3(1024 / 32, 2048 / 32), tb, 0, stream>>>(W_out, W_outT, 2048, 1024);
  // 3. depthwise conv + silu -> xbc bf16
  conv_silu_kernel<<<(TOKENS * D_DIM / 2) / 256, 256, 0, stream>>>(xb, conv_w, conv_b, xbc);
  // 4. dt = softplus(xbc @ W_dt + b_dt) -> fp32
  gemm_bf16<<<dim3(D_DIM / BN, TOKENS / BM), 256, 0, stream>>>(
      xbc, W_dtT, dtY, D_DIM, D_DIM, D_DIM, D_DIM, b_dt, nullptr, 1, 0);
  // 5. Bi/Ci projections
  bc_kernel<<<TOKENS, 256, 0, stream>>>(xbc, W_B, W_C, Bi, Ci);
  // 6. chunked scan: local -> combine -> rescan+gate (writes ybf, xb region dead)
  scan1_kernel<<<dim3(D_DIM / 16, CH, B_DIM), 256, 0, stream>>>(
      dtY, xbc, Bi, A_log, hfin, dtsum);
  scan2_kernel<<<(B_DIM * D_DIM * N_STATE) / 256, 256, 0, stream>>>(
      hfin, dtsum, A_log, hstart);
  scan3_kernel<<<dim3(D_DIM / 16, CH, B_DIM), 256, 0, stream>>>(
      dtY, xbc, Bi, Ci, A_log, hstart, z, D_param, ybf);
  // 7. out = x + y @ W_out   (fp32 out + residual)
  gemm_bf16<<<dim3(H_DIM / BN, TOKENS / BM), 256, 0, stream>>>(
      ybf, W_outT, out, D_DIM, D_DIM, D_DIM, H_DIM, nullptr, x, 0, 0);
}

// Round 5
// 746.808 us; speedup vs baseline: 3.8900x; 1.5064x over previous
//
#include <hip/hip_runtime.h>
#include <hip/hip_bf16.h>
#include <cstdint>
#include <cstddef>

#define B_DIM 4
#define L_DIM 2048
#define H_DIM 1024
#define D_DIM 2048
#define N_STATE 16
#define TOKENS (B_DIM * L_DIM)   // 8192
#define CH 16                    // scan chunks
#define LC (L_DIM / CH)          // 128 steps per chunk

typedef __bf16 bf16x8 __attribute__((ext_vector_type(8)));
typedef float f32x4 __attribute__((ext_vector_type(4)));

__device__ __forceinline__ float sigmoidf_(float x) { return 1.f / (1.f + __expf(-x)); }
__device__ __forceinline__ float softplusf_(float x) {
  return fmaxf(x, 0.f) + log1pf(__expf(-fabsf(x)));
}
__device__ __forceinline__ void gl_lds16(const void* g, void* l) {
  __builtin_amdgcn_global_load_lds(
      (const __attribute__((address_space(1))) unsigned int*)g,
      (__attribute__((address_space(3))) unsigned int*)l, 16, 0, 0);
}

// ---------------- LayerNorm -> bf16: one block per token ----------------
__global__ __launch_bounds__(256) void ln_kernel(const float* __restrict__ x,
    const float* __restrict__ gamma, const float* __restrict__ beta,
    __hip_bfloat16* __restrict__ out) {
  int row = blockIdx.x;
  int t = threadIdx.x;
  const float* px = x + (size_t)row * H_DIM;
  float4 v = *(const float4*)(px + t * 4);
  float s  = v.x + v.y + v.z + v.w;
  float ss = v.x * v.x + v.y * v.y + v.z * v.z + v.w * v.w;
  for (int off = 32; off > 0; off >>= 1) {
    s  += __shfl_down(s, off);
    ss += __shfl_down(ss, off);
  }
  __shared__ float red[8];
  __shared__ float stats[2];
  int wave = t >> 6, lane = t & 63;
  if (lane == 0) { red[wave] = s; red[4 + wave] = ss; }
  __syncthreads();
  if (t == 0) {
    float S  = red[0] + red[1] + red[2] + red[3];
    float SS = red[4] + red[5] + red[6] + red[7];
    float mu = S / H_DIM;
    float var = SS / H_DIM - mu * mu;
    stats[0] = mu;
    stats[1] = rsqrtf(var + 1e-5f);
  }
  __syncthreads();
  float mu = stats[0], rstd = stats[1];
  float4 g  = *(const float4*)(gamma + t * 4);
  float4 bt = *(const float4*)(beta + t * 4);
  __hip_bfloat16* po = out + (size_t)row * H_DIM + t * 4;
  po[0] = __float2bfloat16((v.x - mu) * rstd * g.x + bt.x);
  po[1] = __float2bfloat16((v.y - mu) * rstd * g.y + bt.y);
  po[2] = __float2bfloat16((v.z - mu) * rstd * g.z + bt.z);
  po[3] = __float2bfloat16((v.w - mu) * rstd * g.w + bt.w);
}

// ---------------- transpose+convert: in fp32 [R][C] -> out bf16 [C][R] ----------------
__global__ void transpose_bf16(const float* __restrict__ in,
                               __hip_bfloat16* __restrict__ out, int R, int C) {
  __shared__ float tile[32][33];
  int c0 = blockIdx.x * 32, r0 = blockIdx.y * 32;
  int tx = threadIdx.x, ty = threadIdx.y;   // (32, 8)
  for (int i = 0; i < 32; i += 8)
    tile[ty + i][tx] = in[(size_t)(r0 + ty + i) * C + c0 + tx];
  __syncthreads();
  for (int i = 0; i < 32; i += 8)
    out[(size_t)(c0 + ty + i) * R + r0 + tx] = __float2bfloat16(tile[tx][ty + i]);
}

// ---------------- bf16 MFMA GEMM (m97 structure): C = A[M,K] @ Bt[N,K]^T ----------------
#define BM 128
#define BN 128
#define BK 32

__global__ __launch_bounds__(256) void gemm_bf16(
    const __hip_bfloat16* __restrict__ A, const __hip_bfloat16* __restrict__ Bt,
    void* __restrict__ Cout, int K, int lda, int ldb, int ldc,
    const float* __restrict__ bias, const float* __restrict__ resid,
    int act, int out_bf16) {
  __shared__ __hip_bfloat16 As[BM * BK];
  __shared__ __hip_bfloat16 Bs[BN * BK];
  int t = threadIdx.x;
  int m0 = blockIdx.y * BM, n0 = blockIdx.x * BN;
  int wave = t >> 6, lane = t & 63;
  int quad = lane >> 4, l16 = lane & 15;
  int wm = (wave >> 1) * 64, wn = (wave & 1) * 64;

  f32x4 acc[4][4] = {};

  int srow = t >> 2;
  int scol = (t & 3) * 8;
  const __hip_bfloat16* Ag  = A  + (size_t)(m0 + srow) * lda + scol;
  const __hip_bfloat16* Ag2 = Ag + (size_t)64 * lda;
  const __hip_bfloat16* Bg  = Bt + (size_t)(n0 + srow) * ldb + scol;
  const __hip_bfloat16* Bg2 = Bg + (size_t)64 * ldb;
  __hip_bfloat16* Asl  = &As[t * 8];
  __hip_bfloat16* Asl2 = Asl + 64 * BK;
  __hip_bfloat16* Bsl  = &Bs[t * 8];
  __hip_bfloat16* Bsl2 = Bsl + 64 * BK;

  for (int k0 = 0; k0 < K; k0 += BK) {
    __syncthreads();
    gl_lds16(Ag  + k0, Asl);
    gl_lds16(Ag2 + k0, Asl2);
    gl_lds16(Bg  + k0, Bsl);
    gl_lds16(Bg2 + k0, Bsl2);
    __syncthreads();
    bf16x8 af[4], bf_[4];
#pragma unroll
    for (int i = 0; i < 4; ++i) {
      af[i]  = *(const bf16x8*)&As[(wm + i * 16 + l16) * BK + quad * 8];
      bf_[i] = *(const bf16x8*)&Bs[(wn + i * 16 + l16) * BK + quad * 8];
    }
#pragma unroll
    for (int i = 0; i < 4; ++i)
#pragma unroll
      for (int j = 0; j < 4; ++j)
        acc[i][j] = __builtin_amdgcn_mfma_f32_16x16x32_bf16(af[i], bf_[j], acc[i][j], 0, 0, 0);
  }

  float* Cf = (float*)Cout;
  __hip_bfloat16* Cb = (__hip_bfloat16*)Cout;
#pragma unroll
  for (int i = 0; i < 4; ++i) {
    int row0 = m0 + wm + i * 16 + quad * 4;   // C/D: col=lane&15, row=quad*4+reg
#pragma unroll
    for (int j = 0; j < 4; ++j) {
      int col = n0 + wn + j * 16 + l16;
      f32x4 v = acc[i][j];
      if (bias) {
        float bb = bias[col];
        v[0] += bb; v[1] += bb; v[2] += bb; v[3] += bb;
      }
      if (act == 1) {
        v[0] = softplusf_(v[0]); v[1] = softplusf_(v[1]);
        v[2] = softplusf_(v[2]); v[3] = softplusf_(v[3]);
      }
#pragma unroll
      for (int r = 0; r < 4; ++r) {
        size_t idx = (size_t)(row0 + r) * ldc + col;
        float val = v[r];
        if (resid) val += resid[idx];
        if (out_bf16) Cb[idx] = __float2bfloat16(val);
        else          Cf[idx] = val;
      }
    }
  }
}

// ---------------- depthwise conv(3) + SiLU, bf16 in/out ----------------
__global__ __launch_bounds__(256) void conv_silu_kernel(const __hip_bfloat16* __restrict__ xb,
    const float* __restrict__ cw, const float* __restrict__ cb,
    __hip_bfloat16* __restrict__ xbc) {
  size_t i2 = (size_t)blockIdx.x * 256 + threadIdx.x;  // pair index < TOKENS*D_DIM/2
  int dp = (int)(i2 & (D_DIM / 2 - 1));
  size_t tok = i2 >> 10;
  int l = (int)(tok & (L_DIM - 1));
  int d = dp * 2;
  const __hip_bfloat162* base = (const __hip_bfloat162*)xb + i2;
  __hip_bfloat162 cc = base[0];
  float v0 = cw[d * 3 + 1] * __bfloat162float(cc.x) + cb[d];
  float v1 = cw[d * 3 + 4] * __bfloat162float(cc.y) + cb[d + 1];
  if (l > 0) {
    __hip_bfloat162 pm = base[-(D_DIM / 2)];
    v0 += cw[d * 3 + 0] * __bfloat162float(pm.x);
    v1 += cw[d * 3 + 3] * __bfloat162float(pm.y);
  }
  if (l < L_DIM - 1) {
    __hip_bfloat162 pp = base[D_DIM / 2];
    v0 += cw[d * 3 + 2] * __bfloat162float(pp.x);
    v1 += cw[d * 3 + 5] * __bfloat162float(pp.y);
  }
  v0 = v0 * sigmoidf_(v0);
  v1 = v1 * sigmoidf_(v1);
  __hip_bfloat162 o;
  o.x = __float2bfloat16(v0);
  o.y = __float2bfloat16(v1);
  ((__hip_bfloat162*)xbc)[i2] = o;
}

// ---------------- B/C projections: one block per token row ----------------
__global__ __launch_bounds__(256) void bc_kernel(const __hip_bfloat16* __restrict__ xbc,
    const float* __restrict__ WB, const float* __restrict__ WC,
    float* __restrict__ Bi, float* __restrict__ Ci) {
  __shared__ float sA[D_DIM];
  __shared__ float red[8][32];
  int m = blockIdx.x;
  const __hip_bfloat162* a = (const __hip_bfloat162*)(xbc + (size_t)m * D_DIM);
  for (int i = threadIdx.x; i < D_DIM / 2; i += 256) {
    __hip_bfloat162 p = a[i];
    sA[2 * i]     = __bfloat162float(p.x);
    sA[2 * i + 1] = __bfloat162float(p.y);
  }
  __syncthreads();
  int col = threadIdx.x & 31, slice = threadIdx.x >> 5;
  const float* W = (col < 16) ? WB : WC;
  int c = col & 15;
  float s = 0.f;
  int k0 = slice * 256;
  for (int k = 0; k < 256; ++k) s += sA[k0 + k] * W[(k0 + k) * N_STATE + c];
  red[slice][col] = s;
  __syncthreads();
  if (threadIdx.x < 32) {
    float tsum = 0.f;
#pragma unroll
    for (int i = 0; i < 8; ++i) tsum += red[i][col];
    if (col < 16) Bi[(size_t)m * N_STATE + col] = tsum;
    else          Ci[(size_t)m * N_STATE + (col - 16)] = tsum;
  }
}

// ---------------- chunked scan phase 1: one lane per (b,chunk,d), h[16] in regs ----
// grid = (D/256, CH, B), block 256. Bi chunk staged in LDS (broadcast reads).
__global__ __launch_bounds__(256) void scan1_kernel(const float* __restrict__ dt,
    const __hip_bfloat16* __restrict__ xbc, const float* __restrict__ Bi,
    const float* __restrict__ A_log, float* __restrict__ hfin,
    float* __restrict__ dtsum) {
  __shared__ float Bsh[LC * N_STATE];   // 8 KB
  int t = threadIdx.x;
  int d = blockIdx.x * 256 + t;
  int c = blockIdx.y, b = blockIdx.z;
  size_t base = (size_t)b * L_DIM + (size_t)c * LC;
  // stage B chunk (contiguous, coalesced)
  {
    const float4* Bg = (const float4*)(Bi + base * N_STATE);
    float4* Bd = (float4*)Bsh;
    for (int i = t; i < LC * N_STATE / 4; i += 256) Bd[i] = Bg[i];
  }
  float Aneg[N_STATE];
  {
    const float4* Ap = (const float4*)(A_log + (size_t)d * N_STATE);
#pragma unroll
    for (int q = 0; q < 4; ++q) {
      float4 av = Ap[q];
      Aneg[4 * q + 0] = -__expf(av.x);
      Aneg[4 * q + 1] = -__expf(av.y);
      Aneg[4 * q + 2] = -__expf(av.z);
      Aneg[4 * q + 3] = -__expf(av.w);
    }
  }
  __syncthreads();
  const float* dtp = dt + base * D_DIM + d;
  const __hip_bfloat16* xp = xbc + base * D_DIM + d;
  float h[N_STATE];
#pragma unroll
  for (int n = 0; n < N_STATE; ++n) h[n] = 0.f;
  float ds = 0.f;
  float dtv = dtp[0], xv = __bfloat162float(xp[0]);
  for (int i = 0; i < LC; ++i) {
    int ip = (i < LC - 1) ? i + 1 : i;   // clamped prefetch
    float dt2 = dtp[(size_t)ip * D_DIM];
    float x2  = __bfloat162float(xp[(size_t)ip * D_DIM]);
    float dtx = dtv * xv;
    ds += dtv;
    const float4* Brow = (const float4*)&Bsh[i * N_STATE];
#pragma unroll
    for (int q = 0; q < 4; ++q) {
      float4 bv = Brow[q];
      h[4*q+0] = __expf(dtv * Aneg[4*q+0]) * h[4*q+0] + dtx * bv.x;
      h[4*q+1] = __expf(dtv * Aneg[4*q+1]) * h[4*q+1] + dtx * bv.y;
      h[4*q+2] = __expf(dtv * Aneg[4*q+2]) * h[4*q+2] + dtx * bv.z;
      h[4*q+3] = __expf(dtv * Aneg[4*q+3]) * h[4*q+3] + dtx * bv.w;
    }
    dtv = dt2; xv = x2;
  }
  float* ho = hfin + (((size_t)b * CH + c) * D_DIM + d) * N_STATE;
#pragma unroll
  for (int q = 0; q < 4; ++q) {
    float4 v; v.x = h[4*q]; v.y = h[4*q+1]; v.z = h[4*q+2]; v.w = h[4*q+3];
    ((float4*)ho)[q] = v;
  }
  dtsum[((size_t)b * CH + c) * D_DIM + d] = ds;
}

// ---------------- chunked scan phase 2: combine across chunks ----------------
__global__ __launch_bounds__(256) void scan2_kernel(const float* __restrict__ hfin,
    const float* __restrict__ dtsum, const float* __restrict__ A_log,
    float* __restrict__ hstart) {
  int tid = blockIdx.x * 256 + threadIdx.x;   // < B*D*N = 131072
  int n = tid & 15;
  int d = (tid >> 4) & (D_DIM - 1);
  int b = tid >> 15;
  float Aneg = -__expf(A_log[d * N_STATE + n]);
  float run = 0.f;
  for (int c = 0; c < CH; ++c) {
    size_t o = (((size_t)b * CH + c) * D_DIM + d) * N_STATE + n;
    hstart[o] = run;
    run = __expf(Aneg * dtsum[((size_t)b * CH + c) * D_DIM + d]) * run + hfin[o];
  }
}

// ---------------- chunked scan phase 3: rescan + fused gate, h[16] in regs ----------
__global__ __launch_bounds__(256) void scan3_kernel(const float* __restrict__ dt,
    const __hip_bfloat16* __restrict__ xbc, const float* __restrict__ Bi,
    const float* __restrict__ Ci, const float* __restrict__ A_log,
    const float* __restrict__ hstart, const __hip_bfloat16* __restrict__ z,
    const float* __restrict__ Dp, __hip_bfloat16* __restrict__ yo) {
  __shared__ float Bsh[LC * N_STATE];   // 8 KB
  __shared__ float Csh[LC * N_STATE];   // 8 KB
  int t = threadIdx.x;
  int d = blockIdx.x * 256 + t;
  int c = blockIdx.y, b = blockIdx.z;
  size_t base = (size_t)b * L_DIM + (size_t)c * LC;
  {
    const float4* Bg = (const float4*)(Bi + base * N_STATE);
    const float4* Cg = (const float4*)(Ci + base * N_STATE);
    float4* Bd = (float4*)Bsh;
    float4* Cd = (float4*)Csh;
    for (int i = t; i < LC * N_STATE / 4; i += 256) { Bd[i] = Bg[i]; Cd[i] = Cg[i]; }
  }
  float Aneg[N_STATE];
  {
    const float4* Ap = (const float4*)(A_log + (size_t)d * N_STATE);
#pragma unroll
    for (int q = 0; q < 4; ++q) {
      float4 av = Ap[q];
      Aneg[4 * q + 0] = -__expf(av.x);
      Aneg[4 * q + 1] = -__expf(av.y);
      Aneg[4 * q + 2] = -__expf(av.z);
      Aneg[4 * q + 3] = -__expf(av.w);
    }
  }
  float h[N_STATE];
  {
    const float4* hs = (const float4*)(hstart + (((size_t)b * CH + c) * D_DIM + d) * N_STATE);
#pragma unroll
    for (int q = 0; q < 4; ++q) {
      float4 v = hs[q];
      h[4*q] = v.x; h[4*q+1] = v.y; h[4*q+2] = v.z; h[4*q+3] = v.w;
    }
  }
  float Dv = Dp[d];
  __syncthreads();
  const float* dtp = dt + base * D_DIM + d;
  const __hip_bfloat16* xp = xbc + base * D_DIM + d;
  const __hip_bfloat16* zp = z + base * D_DIM + d;
  __hip_bfloat16* yp = yo + base * D_DIM + d;
  float dtv = dtp[0], xv = __bfloat162float(xp[0]);
  float zv = __bfloat162float(zp[0]);
  for (int i = 0; i < LC; ++i) {
    int ip = (i < LC - 1) ? i + 1 : i;   // clamped prefetch
    float dt2 = dtp[(size_t)ip * D_DIM];
    float x2  = __bfloat162float(xp[(size_t)ip * D_DIM]);
    float z2  = __bfloat162float(zp[(size_t)ip * D_DIM]);
    float dtx = dtv * xv;
    const float4* Brow = (const float4*)&Bsh[i * N_STATE];
    const float4* Crow = (const float4*)&Csh[i * N_STATE];
    float yv = 0.f;
#pragma unroll
    for (int q = 0; q < 4; ++q) {
      float4 bv = Brow[q];
      float4 cv = Crow[q];
      h[4*q+0] = __expf(dtv * Aneg[4*q+0]) * h[4*q+0] + dtx * bv.x;
      h[4*q+1] = __expf(dtv * Aneg[4*q+1]) * h[4*q+1] + dtx * bv.y;
      h[4*q+2] = __expf(dtv * Aneg[4*q+2]) * h[4*q+2] + dtx * bv.z;
      h[4*q+3] = __expf(dtv * Aneg[4*q+3]) * h[4*q+3] + dtx * bv.w;
      yv += h[4*q+0] * cv.x + h[4*q+1] * cv.y + h[4*q+2] * cv.z + h[4*q+3] * cv.w;
    }
    float g = zv * sigmoidf_(zv);
    yp[(size_t)i * D_DIM] = __float2bfloat16((yv + Dv * xv) * g);
    dtv = dt2; xv = x2; zv = z2;
  }
}

extern "C" void kernel_launch(void* const* d_in, const int* in_sizes, int n_in,
                              void* d_out, int out_size, void* d_ws, size_t ws_size,
                              hipStream_t stream) {
  const float* x          = (const float*)d_in[0];
  const float* norm_scale = (const float*)d_in[1];
  const float* norm_bias  = (const float*)d_in[2];
  const float* W_in       = (const float*)d_in[3];
  const float* conv_w     = (const float*)d_in[4];
  const float* conv_b     = (const float*)d_in[5];
  const float* W_dt       = (const float*)d_in[6];
  const float* b_dt       = (const float*)d_in[7];
  const float* A_log      = (const float*)d_in[8];
  const float* D_param    = (const float*)d_in[9];
  const float* W_B        = (const float*)d_in[10];
  const float* W_C        = (const float*)d_in[11];
  const float* W_out      = (const float*)d_in[12];
  float* out = (float*)d_out;

  // Workspace layout (193 MB, same proven footprint as R3/R4):
  //  S0 [  0, 16M): xn bf16 (dead after GEMM1b) -> W_outT [0,4M),
  //                 hfin fp32 [4,12M), dtsum fp32 [12,12.5M)
  //  S1 [ 16, 48M): xb bf16 (GEMM1a->conv) -> ybf bf16 (scan3 -> GEMM3)
  //  S2 [ 48, 80M): z bf16 (GEMM1b->scan3)
  //  S3 [ 80,112M): xbc bf16 (conv->scan)
  //  S4 [112,176M): dt fp32 (GEMM2->scan)
  //  S5 [176,177M): Bi, Ci fp32
  //  S6 [177,185M): W_inT bf16 (dead after GEMM1b) -> hstart fp32 (8M)
  //  S7 [185,193M): W_dtT bf16
  const size_t MB = 1024 * 1024;
  const size_t NEEDED = 193 * MB;
  if (ws_size < NEEDED) return;   // diagnostic bail: ws too small

  char* ws = (char*)d_ws;
  __hip_bfloat16* xn     = (__hip_bfloat16*)(ws);
  __hip_bfloat16* W_outT = (__hip_bfloat16*)(ws);            // [0,4M) after xn dead
  float*          hfin   = (float*)(ws + 4 * MB);            // [4,12M)
  float*          dtsum  = (float*)(ws + 12 * MB);           // [12,12.5M)
  __hip_bfloat16* xb     = (__hip_bfloat16*)(ws + 16 * MB);
  __hip_bfloat16* ybf    = (__hip_bfloat16*)(ws + 16 * MB);  // after conv
  __hip_bfloat16* z      = (__hip_bfloat16*)(ws + 48 * MB);
  __hip_bfloat16* xbc    = (__hip_bfloat16*)(ws + 80 * MB);
  float*          dtY    = (float*)(ws + 112 * MB);
  float*          Bi     = (float*)(ws + 176 * MB);
  float*          Ci     = Bi + (size_t)TOKENS * N_STATE;
  __hip_bfloat16* W_inT  = (__hip_bfloat16*)(ws + 177 * MB);
  float*          hstart = (float*)(ws + 177 * MB);          // after W_inT dead
  __hip_bfloat16* W_dtT  = (__hip_bfloat16*)(ws + 185 * MB);

  dim3 tb(32, 8);
  // 0. weight transpose+convert
  transpose_bf16<<<dim3(4096 / 32, 1024 / 32), tb, 0, stream>>>(W_in, W_inT, 1024, 4096);
  transpose_bf16<<<dim3(2048 / 32, 2048 / 32), tb, 0, stream>>>(W_dt, W_dtT, 2048, 2048);
  // 1. LayerNorm -> bf16
  ln_kernel<<<TOKENS, 256, 0, stream>>>(x, norm_scale, norm_bias, xn);
  // 2a. xb = xn @ W_in[:, :2048]
  gemm_bf16<<<dim3(D_DIM / BN, TOKENS / BM), 256, 0, stream>>>(
      xn, W_inT, xb, H_DIM, H_DIM, H_DIM, D_DIM, nullptr, nullptr, 0, 1);
  // 2b. z = xn @ W_in[:, 2048:]
  gemm_bf16<<<dim3(D_DIM / BN, TOKENS / BM), 256, 0, stream>>>(
      xn, W_inT + (size_t)D_DIM * H_DIM, z, H_DIM, H_DIM, H_DIM, D_DIM,
      nullptr, nullptr, 0, 1);
  // (xn dead) convert W_out into S0
  transpose_bf16<<<dim3(1024 / 32, 2048 / 32), tb, 0, stream>>>(W_out, W_outT, 2048, 1024);
  // 3. depthwise conv + silu -> xbc bf16
  conv_silu_kernel<<<(TOKENS * D_DIM / 2) / 256, 256, 0, stream>>>(xb, conv_w, conv_b, xbc);
  // 4. dt = softplus(xbc @ W_dt + b_dt) -> fp32
  gemm_bf16<<<dim3(D_DIM / BN, TOKENS / BM), 256, 0, stream>>>(
      xbc, W_dtT, dtY, D_DIM, D_DIM, D_DIM, D_DIM, b_dt, nullptr, 1, 0);
  // 5. Bi/Ci projections
  bc_kernel<<<TOKENS, 256, 0, stream>>>(xbc, W_B, W_C, Bi, Ci);
  // 6. chunked scan: local -> combine -> rescan+gate (writes ybf, xb region dead)
  scan1_kernel<<<dim3(D_DIM / 256, CH, B_DIM), 256, 0, stream>>>(
      dtY, xbc, Bi, A_log, hfin, dtsum);
  scan2_kernel<<<(B_DIM * D_DIM * N_STATE) / 256, 256, 0, stream>>>(
      hfin, dtsum, A_log, hstart);
  scan3_kernel<<<dim3(D_DIM / 256, CH, B_DIM), 256, 0, stream>>>(
      dtY, xbc, Bi, Ci, A_log, hstart, z, D_param, ybf);
  // 7. out = x + y @ W_out   (fp32 out + residual)
  gemm_bf16<<<dim3(H_DIM / BN, TOKENS / BM), 256, 0, stream>>>(
      ybf, W_outT, out, D_DIM, D_DIM, D_DIM, H_DIM, nullptr, x, 0, 0);
}

// Round 6
// 681.021 us; speedup vs baseline: 4.2658x; 1.0966x over previous
//
#include <hip/hip_runtime.h>
#include <hip/hip_bf16.h>
#include <cstdint>
#include <cstddef>

#define B_DIM 4
#define L_DIM 2048
#define H_DIM 1024
#define D_DIM 2048
#define N_STATE 16
#define TOKENS (B_DIM * L_DIM)   // 8192
#define CH 16                    // scan chunks
#define LC (L_DIM / CH)          // 128 steps per chunk

typedef __bf16 bf16x8 __attribute__((ext_vector_type(8)));
typedef float f32x4 __attribute__((ext_vector_type(4)));

__device__ __forceinline__ float sigmoidf_(float x) { return 1.f / (1.f + __expf(-x)); }
__device__ __forceinline__ float softplusf_(float x) {
  return fmaxf(x, 0.f) + log1pf(__expf(-fabsf(x)));
}
__device__ __forceinline__ void gl_lds16(const void* g, void* l) {
  __builtin_amdgcn_global_load_lds(
      (const __attribute__((address_space(1))) unsigned int*)g,
      (__attribute__((address_space(3))) unsigned int*)l, 16, 0, 0);
}

// ---------------- LayerNorm -> bf16: one block per token ----------------
__global__ __launch_bounds__(256) void ln_kernel(const float* __restrict__ x,
    const float* __restrict__ gamma, const float* __restrict__ beta,
    __hip_bfloat16* __restrict__ out) {
  int row = blockIdx.x;
  int t = threadIdx.x;
  const float* px = x + (size_t)row * H_DIM;
  float4 v = *(const float4*)(px + t * 4);
  float s  = v.x + v.y + v.z + v.w;
  float ss = v.x * v.x + v.y * v.y + v.z * v.z + v.w * v.w;
  for (int off = 32; off > 0; off >>= 1) {
    s  += __shfl_down(s, off);
    ss += __shfl_down(ss, off);
  }
  __shared__ float red[8];
  __shared__ float stats[2];
  int wave = t >> 6, lane = t & 63;
  if (lane == 0) { red[wave] = s; red[4 + wave] = ss; }
  __syncthreads();
  if (t == 0) {
    float S  = red[0] + red[1] + red[2] + red[3];
    float SS = red[4] + red[5] + red[6] + red[7];
    float mu = S / H_DIM;
    float var = SS / H_DIM - mu * mu;
    stats[0] = mu;
    stats[1] = rsqrtf(var + 1e-5f);
  }
  __syncthreads();
  float mu = stats[0], rstd = stats[1];
  float4 g  = *(const float4*)(gamma + t * 4);
  float4 bt = *(const float4*)(beta + t * 4);
  __hip_bfloat16* po = out + (size_t)row * H_DIM + t * 4;
  po[0] = __float2bfloat16((v.x - mu) * rstd * g.x + bt.x);
  po[1] = __float2bfloat16((v.y - mu) * rstd * g.y + bt.y);
  po[2] = __float2bfloat16((v.z - mu) * rstd * g.z + bt.z);
  po[3] = __float2bfloat16((v.w - mu) * rstd * g.w + bt.w);
}

// ---------------- transpose+convert: in fp32 [R][C] -> out bf16 [C][R] ----------------
__global__ void transpose_bf16(const float* __restrict__ in,
                               __hip_bfloat16* __restrict__ out, int R, int C) {
  __shared__ float tile[32][33];
  int c0 = blockIdx.x * 32, r0 = blockIdx.y * 32;
  int tx = threadIdx.x, ty = threadIdx.y;   // (32, 8)
  for (int i = 0; i < 32; i += 8)
    tile[ty + i][tx] = in[(size_t)(r0 + ty + i) * C + c0 + tx];
  __syncthreads();
  for (int i = 0; i < 32; i += 8)
    out[(size_t)(c0 + ty + i) * R + r0 + tx] = __float2bfloat16(tile[tx][ty + i]);
}

// ---------------- bf16 MFMA GEMM: C = A[M,K] @ Bt[N,K]^T ----------------
// 128x128 tile, BK=64, XOR-swizzled LDS (conflict-free ds_read_b128),
// 4 waves x (64x64 via 4x4 mfma_f32_16x16x32_bf16, 2 k-steps per K-iter).
// Csplit: cols >= nsplit go to Csplit (bf16 path only; split is wave-uniform).
#define BM 128
#define BN 128
#define BK 64

__global__ __launch_bounds__(256) void gemm_bf16(
    const __hip_bfloat16* __restrict__ A, const __hip_bfloat16* __restrict__ Bt,
    void* __restrict__ Cout, __hip_bfloat16* __restrict__ Csplit, int nsplit,
    int K, int lda, int ldb, int ldc,
    const float* __restrict__ bias, const float* __restrict__ resid,
    int act, int out_bf16) {
  __shared__ __hip_bfloat16 As[BM * BK];   // 16 KB
  __shared__ __hip_bfloat16 Bs[BN * BK];   // 16 KB
  int t = threadIdx.x;
  int m0 = blockIdx.y * BM, n0 = blockIdx.x * BN;
  int wave = t >> 6, lane = t & 63;
  int quad = lane >> 4, l16 = lane & 15;
  int wm = (wave >> 1) * 64, wn = (wave & 1) * 64;

  f32x4 acc[4][4] = {};

  // staging map: 4 issues of 32 rows each; thread t -> row j*32+(t>>3),
  // LDS 16B chunk slot (t&7); global chunk cdata = cslot ^ (row&7) (XOR swizzle).
  int srow  = t >> 3;            // 0..31
  int cslot = t & 7;
  int cdata = cslot ^ (srow & 7);  // (j*32 multiple of 8 -> row&7 == srow&7)
  const __hip_bfloat16* Ag[4];
  const __hip_bfloat16* Bg[4];
  __hip_bfloat16* Asl[4];
  __hip_bfloat16* Bsl[4];
#pragma unroll
  for (int j = 0; j < 4; ++j) {
    Ag[j]  = A  + (size_t)(m0 + j * 32 + srow) * lda + cdata * 8;
    Bg[j]  = Bt + (size_t)(n0 + j * 32 + srow) * ldb + cdata * 8;
    Asl[j] = &As[(j * 32 + srow) * BK + cslot * 8];  // = base + j*4KB + t*16B
    Bsl[j] = &Bs[(j * 32 + srow) * BK + cslot * 8];
  }

  for (int k0 = 0; k0 < K; k0 += BK) {
    __syncthreads();
#pragma unroll
    for (int j = 0; j < 4; ++j) {
      gl_lds16(Ag[j] + k0, Asl[j]);
      gl_lds16(Bg[j] + k0, Bsl[j]);
    }
    __syncthreads();
#pragma unroll
    for (int s = 0; s < 2; ++s) {
      // fragment read: row r, k-chunk cdata=s*4+quad -> slot cs = cdata^(r&7);
      // r&7 == l16&7 for all i (wm, i*16 are multiples of 8/16).
      int cs = ((s * 4 + quad) ^ (l16 & 7)) * 8;
      bf16x8 af[4], bf_[4];
#pragma unroll
      for (int i = 0; i < 4; ++i) {
        af[i]  = *(const bf16x8*)&As[(wm + i * 16 + l16) * BK + cs];
        bf_[i] = *(const bf16x8*)&Bs[(wn + i * 16 + l16) * BK + cs];
      }
#pragma unroll
      for (int i = 0; i < 4; ++i)
#pragma unroll
        for (int j = 0; j < 4; ++j)
          acc[i][j] = __builtin_amdgcn_mfma_f32_16x16x32_bf16(af[i], bf_[j], acc[i][j], 0, 0, 0);
    }
  }

  float* Cf = (float*)Cout;
  __hip_bfloat16* Cb = (__hip_bfloat16*)Cout;
#pragma unroll
  for (int i = 0; i < 4; ++i) {
    int row0 = m0 + wm + i * 16 + quad * 4;   // C/D: col=lane&15, row=quad*4+reg
#pragma unroll
    for (int j = 0; j < 4; ++j) {
      int col = n0 + wn + j * 16 + l16;
      f32x4 v = acc[i][j];
      if (bias) {
        float bb = bias[col];
        v[0] += bb; v[1] += bb; v[2] += bb; v[3] += bb;
      }
      if (act == 1) {
        v[0] = softplusf_(v[0]); v[1] = softplusf_(v[1]);
        v[2] = softplusf_(v[2]); v[3] = softplusf_(v[3]);
      }
      __hip_bfloat16* cbp = Cb;
      int ccol = col;
      if (Csplit && col >= nsplit) { cbp = Csplit; ccol = col - nsplit; }
#pragma unroll
      for (int r = 0; r < 4; ++r) {
        float val = v[r];
        if (resid) val += resid[(size_t)(row0 + r) * ldc + col];
        if (out_bf16) cbp[(size_t)(row0 + r) * ldc + ccol] = __float2bfloat16(val);
        else          Cf[(size_t)(row0 + r) * ldc + col] = val;
      }
    }
  }
}

// ---------------- depthwise conv(3) + SiLU, bf16 in/out ----------------
__global__ __launch_bounds__(256) void conv_silu_kernel(const __hip_bfloat16* __restrict__ xb,
    const float* __restrict__ cw, const float* __restrict__ cb,
    __hip_bfloat16* __restrict__ xbc) {
  size_t i2 = (size_t)blockIdx.x * 256 + threadIdx.x;  // pair index < TOKENS*D_DIM/2
  int dp = (int)(i2 & (D_DIM / 2 - 1));
  size_t tok = i2 >> 10;
  int l = (int)(tok & (L_DIM - 1));
  int d = dp * 2;
  const __hip_bfloat162* base = (const __hip_bfloat162*)xb + i2;
  __hip_bfloat162 cc = base[0];
  float v0 = cw[d * 3 + 1] * __bfloat162float(cc.x) + cb[d];
  float v1 = cw[d * 3 + 4] * __bfloat162float(cc.y) + cb[d + 1];
  if (l > 0) {
    __hip_bfloat162 pm = base[-(D_DIM / 2)];
    v0 += cw[d * 3 + 0] * __bfloat162float(pm.x);
    v1 += cw[d * 3 + 3] * __bfloat162float(pm.y);
  }
  if (l < L_DIM - 1) {
    __hip_bfloat162 pp = base[D_DIM / 2];
    v0 += cw[d * 3 + 2] * __bfloat162float(pp.x);
    v1 += cw[d * 3 + 5] * __bfloat162float(pp.y);
  }
  v0 = v0 * sigmoidf_(v0);
  v1 = v1 * sigmoidf_(v1);
  __hip_bfloat162 o;
  o.x = __float2bfloat16(v0);
  o.y = __float2bfloat16(v1);
  ((__hip_bfloat162*)xbc)[i2] = o;
}

// ---------------- B/C projections: one block per token row ----------------
__global__ __launch_bounds__(256) void bc_kernel(const __hip_bfloat16* __restrict__ xbc,
    const float* __restrict__ WB, const float* __restrict__ WC,
    float* __restrict__ Bi, float* __restrict__ Ci) {
  __shared__ float sA[D_DIM];
  __shared__ float red[8][32];
  int m = blockIdx.x;
  const __hip_bfloat162* a = (const __hip_bfloat162*)(xbc + (size_t)m * D_DIM);
  for (int i = threadIdx.x; i < D_DIM / 2; i += 256) {
    __hip_bfloat162 p = a[i];
    sA[2 * i]     = __bfloat162float(p.x);
    sA[2 * i + 1] = __bfloat162float(p.y);
  }
  __syncthreads();
  int col = threadIdx.x & 31, slice = threadIdx.x >> 5;
  const float* W = (col < 16) ? WB : WC;
  int c = col & 15;
  float s = 0.f;
  int k0 = slice * 256;
  for (int k = 0; k < 256; ++k) s += sA[k0 + k] * W[(k0 + k) * N_STATE + c];
  red[slice][col] = s;
  __syncthreads();
  if (threadIdx.x < 32) {
    float tsum = 0.f;
#pragma unroll
    for (int i = 0; i < 8; ++i) tsum += red[i][col];
    if (col < 16) Bi[(size_t)m * N_STATE + col] = tsum;
    else          Ci[(size_t)m * N_STATE + (col - 16)] = tsum;
  }
}

// ---------------- chunked scan phase 1: one lane per (b,chunk,d), h[16] in regs ----
__global__ __launch_bounds__(256) void scan1_kernel(const float* __restrict__ dt,
    const __hip_bfloat16* __restrict__ xbc, const float* __restrict__ Bi,
    const float* __restrict__ A_log, float* __restrict__ hfin,
    float* __restrict__ dtsum) {
  __shared__ float Bsh[LC * N_STATE];   // 8 KB
  int t = threadIdx.x;
  int d = blockIdx.x * 256 + t;
  int c = blockIdx.y, b = blockIdx.z;
  size_t base = (size_t)b * L_DIM + (size_t)c * LC;
  {
    const float4* Bg = (const float4*)(Bi + base * N_STATE);
    float4* Bd = (float4*)Bsh;
    for (int i = t; i < LC * N_STATE / 4; i += 256) Bd[i] = Bg[i];
  }
  float Aneg[N_STATE];
  {
    const float4* Ap = (const float4*)(A_log + (size_t)d * N_STATE);
#pragma unroll
    for (int q = 0; q < 4; ++q) {
      float4 av = Ap[q];
      Aneg[4 * q + 0] = -__expf(av.x);
      Aneg[4 * q + 1] = -__expf(av.y);
      Aneg[4 * q + 2] = -__expf(av.z);
      Aneg[4 * q + 3] = -__expf(av.w);
    }
  }
  __syncthreads();
  const float* dtp = dt + base * D_DIM + d;
  const __hip_bfloat16* xp = xbc + base * D_DIM + d;
  float h[N_STATE];
#pragma unroll
  for (int n = 0; n < N_STATE; ++n) h[n] = 0.f;
  float ds = 0.f;
  float dtv = dtp[0], xv = __bfloat162float(xp[0]);
  for (int i = 0; i < LC; ++i) {
    int ip = (i < LC - 1) ? i + 1 : i;   // clamped prefetch
    float dt2 = dtp[(size_t)ip * D_DIM];
    float x2  = __bfloat162float(xp[(size_t)ip * D_DIM]);
    float dtx = dtv * xv;
    ds += dtv;
    const float4* Brow = (const float4*)&Bsh[i * N_STATE];
#pragma unroll
    for (int q = 0; q < 4; ++q) {
      float4 bv = Brow[q];
      h[4*q+0] = __expf(dtv * Aneg[4*q+0]) * h[4*q+0] + dtx * bv.x;
      h[4*q+1] = __expf(dtv * Aneg[4*q+1]) * h[4*q+1] + dtx * bv.y;
      h[4*q+2] = __expf(dtv * Aneg[4*q+2]) * h[4*q+2] + dtx * bv.z;
      h[4*q+3] = __expf(dtv * Aneg[4*q+3]) * h[4*q+3] + dtx * bv.w;
    }
    dtv = dt2; xv = x2;
  }
  float* ho = hfin + (((size_t)b * CH + c) * D_DIM + d) * N_STATE;
#pragma unroll
  for (int q = 0; q < 4; ++q) {
    float4 v; v.x = h[4*q]; v.y = h[4*q+1]; v.z = h[4*q+2]; v.w = h[4*q+3];
    ((float4*)ho)[q] = v;
  }
  dtsum[((size_t)b * CH + c) * D_DIM + d] = ds;
}

// ---------------- chunked scan phase 2: combine across chunks ----------------
__global__ __launch_bounds__(256) void scan2_kernel(const float* __restrict__ hfin,
    const float* __restrict__ dtsum, const float* __restrict__ A_log,
    float* __restrict__ hstart) {
  int tid = blockIdx.x * 256 + threadIdx.x;   // < B*D*N = 131072
  int n = tid & 15;
  int d = (tid >> 4) & (D_DIM - 1);
  int b = tid >> 15;
  float Aneg = -__expf(A_log[d * N_STATE + n]);
  float run = 0.f;
  for (int c = 0; c < CH; ++c) {
    size_t o = (((size_t)b * CH + c) * D_DIM + d) * N_STATE + n;
    hstart[o] = run;
    run = __expf(Aneg * dtsum[((size_t)b * CH + c) * D_DIM + d]) * run + hfin[o];
  }
}

// ---------------- chunked scan phase 3: rescan + fused gate, h[16] in regs ----------
__global__ __launch_bounds__(256) void scan3_kernel(const float* __restrict__ dt,
    const __hip_bfloat16* __restrict__ xbc, const float* __restrict__ Bi,
    const float* __restrict__ Ci, const float* __restrict__ A_log,
    const float* __restrict__ hstart, const __hip_bfloat16* __restrict__ z,
    const float* __restrict__ Dp, __hip_bfloat16* __restrict__ yo) {
  __shared__ float Bsh[LC * N_STATE];   // 8 KB
  __shared__ float Csh[LC * N_STATE];   // 8 KB
  int t = threadIdx.x;
  int d = blockIdx.x * 256 + t;
  int c = blockIdx.y, b = blockIdx.z;
  size_t base = (size_t)b * L_DIM + (size_t)c * LC;
  {
    const float4* Bg = (const float4*)(Bi + base * N_STATE);
    const float4* Cg = (const float4*)(Ci + base * N_STATE);
    float4* Bd = (float4*)Bsh;
    float4* Cd = (float4*)Csh;
    for (int i = t; i < LC * N_STATE / 4; i += 256) { Bd[i] = Bg[i]; Cd[i] = Cg[i]; }
  }
  float Aneg[N_STATE];
  {
    const float4* Ap = (const float4*)(A_log + (size_t)d * N_STATE);
#pragma unroll
    for (int q = 0; q < 4; ++q) {
      float4 av = Ap[q];
      Aneg[4 * q + 0] = -__expf(av.x);
      Aneg[4 * q + 1] = -__expf(av.y);
      Aneg[4 * q + 2] = -__expf(av.z);
      Aneg[4 * q + 3] = -__expf(av.w);
    }
  }
  float h[N_STATE];
  {
    const float4* hs = (const float4*)(hstart + (((size_t)b * CH + c) * D_DIM + d) * N_STATE);
#pragma unroll
    for (int q = 0; q < 4; ++q) {
      float4 v = hs[q];
      h[4*q] = v.x; h[4*q+1] = v.y; h[4*q+2] = v.z; h[4*q+3] = v.w;
    }
  }
  float Dv = Dp[d];
  __syncthreads();
  const float* dtp = dt + base * D_DIM + d;
  const __hip_bfloat16* xp = xbc + base * D_DIM + d;
  const __hip_bfloat16* zp = z + base * D_DIM + d;
  __hip_bfloat16* yp = yo + base * D_DIM + d;
  float dtv = dtp[0], xv = __bfloat162float(xp[0]);
  float zv = __bfloat162float(zp[0]);
  for (int i = 0; i < LC; ++i) {
    int ip = (i < LC - 1) ? i + 1 : i;   // clamped prefetch
    float dt2 = dtp[(size_t)ip * D_DIM];
    float x2  = __bfloat162float(xp[(size_t)ip * D_DIM]);
    float z2  = __bfloat162float(zp[(size_t)ip * D_DIM]);
    float dtx = dtv * xv;
    const float4* Brow = (const float4*)&Bsh[i * N_STATE];
    const float4* Crow = (const float4*)&Csh[i * N_STATE];
    float yv = 0.f;
#pragma unroll
    for (int q = 0; q < 4; ++q) {
      float4 bv = Brow[q];
      float4 cv = Crow[q];
      h[4*q+0] = __expf(dtv * Aneg[4*q+0]) * h[4*q+0] + dtx * bv.x;
      h[4*q+1] = __expf(dtv * Aneg[4*q+1]) * h[4*q+1] + dtx * bv.y;
      h[4*q+2] = __expf(dtv * Aneg[4*q+2]) * h[4*q+2] + dtx * bv.z;
      h[4*q+3] = __expf(dtv * Aneg[4*q+3]) * h[4*q+3] + dtx * bv.w;
      yv += h[4*q+0] * cv.x + h[4*q+1] * cv.y + h[4*q+2] * cv.z + h[4*q+3] * cv.w;
    }
    float g = zv * sigmoidf_(zv);
    yp[(size_t)i * D_DIM] = __float2bfloat16((yv + Dv * xv) * g);
    dtv = dt2; xv = x2; zv = z2;
  }
}

extern "C" void kernel_launch(void* const* d_in, const int* in_sizes, int n_in,
                              void* d_out, int out_size, void* d_ws, size_t ws_size,
                              hipStream_t stream) {
  const float* x          = (const float*)d_in[0];
  const float* norm_scale = (const float*)d_in[1];
  const float* norm_bias  = (const float*)d_in[2];
  const float* W_in       = (const float*)d_in[3];
  const float* conv_w     = (const float*)d_in[4];
  const float* conv_b     = (const float*)d_in[5];
  const float* W_dt       = (const float*)d_in[6];
  const float* b_dt       = (const float*)d_in[7];
  const float* A_log      = (const float*)d_in[8];
  const float* D_param    = (const float*)d_in[9];
  const float* W_B        = (const float*)d_in[10];
  const float* W_C        = (const float*)d_in[11];
  const float* W_out      = (const float*)d_in[12];
  float* out = (float*)d_out;

  // Workspace layout (193 MB, same proven footprint as R3-R5):
  //  S0 [  0, 16M): xn bf16 (dead after GEMM1) -> W_outT [0,4M),
  //                 hfin fp32 [4,12M), dtsum fp32 [12,12.5M)
  //  S1 [ 16, 48M): xb bf16 (GEMM1->conv) -> ybf bf16 (scan3 -> GEMM3)
  //  S2 [ 48, 80M): z bf16 (GEMM1->scan3)
  //  S3 [ 80,112M): xbc bf16 (conv->scan)
  //  S4 [112,176M): dt fp32 (GEMM2->scan)
  //  S5 [176,177M): Bi, Ci fp32
  //  S6 [177,185M): W_inT bf16 (dead after GEMM1) -> hstart fp32 (8M)
  //  S7 [185,193M): W_dtT bf16
  const size_t MB = 1024 * 1024;
  const size_t NEEDED = 193 * MB;
  if (ws_size < NEEDED) return;   // diagnostic bail: ws too small

  char* ws = (char*)d_ws;
  __hip_bfloat16* xn     = (__hip_bfloat16*)(ws);
  __hip_bfloat16* W_outT = (__hip_bfloat16*)(ws);            // [0,4M) after xn dead
  float*          hfin   = (float*)(ws + 4 * MB);            // [4,12M)
  float*          dtsum  = (float*)(ws + 12 * MB);           // [12,12.5M)
  __hip_bfloat16* xb     = (__hip_bfloat16*)(ws + 16 * MB);
  __hip_bfloat16* ybf    = (__hip_bfloat16*)(ws + 16 * MB);  // after conv
  __hip_bfloat16* z      = (__hip_bfloat16*)(ws + 48 * MB);
  __hip_bfloat16* xbc    = (__hip_bfloat16*)(ws + 80 * MB);
  float*          dtY    = (float*)(ws + 112 * MB);
  float*          Bi     = (float*)(ws + 176 * MB);
  float*          Ci     = Bi + (size_t)TOKENS * N_STATE;
  __hip_bfloat16* W_inT  = (__hip_bfloat16*)(ws + 177 * MB);
  float*          hstart = (float*)(ws + 177 * MB);          // after W_inT dead
  __hip_bfloat16* W_dtT  = (__hip_bfloat16*)(ws + 185 * MB);

  dim3 tb(32, 8);
  // 0. weight transpose+convert
  transpose_bf16<<<dim3(4096 / 32, 1024 / 32), tb, 0, stream>>>(W_in, W_inT, 1024, 4096);
  transpose_bf16<<<dim3(2048 / 32, 2048 / 32), tb, 0, stream>>>(W_dt, W_dtT, 2048, 2048);
  // 1. LayerNorm -> bf16
  ln_kernel<<<TOKENS, 256, 0, stream>>>(x, norm_scale, norm_bias, xn);
  // 2. merged [xb|z] = xn @ W_in  (N=4096, split epilogue to xb / z)
  gemm_bf16<<<dim3(2 * D_DIM / BN, TOKENS / BM), 256, 0, stream>>>(
      xn, W_inT, xb, z, D_DIM, H_DIM, H_DIM, H_DIM, D_DIM,
      nullptr, nullptr, 0, 1);
  // (xn dead) convert W_out into S0
  transpose_bf16<<<dim3(1024 / 32, 2048 / 32), tb, 0, stream>>>(W_out, W_outT, 2048, 1024);
  // 3. depthwise conv + silu -> xbc bf16
  conv_silu_kernel<<<(TOKENS * D_DIM / 2) / 256, 256, 0, stream>>>(xb, conv_w, conv_b, xbc);
  // 4. dt = softplus(xbc @ W_dt + b_dt) -> fp32
  gemm_bf16<<<dim3(D_DIM / BN, TOKENS / BM), 256, 0, stream>>>(
      xbc, W_dtT, dtY, nullptr, 1 << 30, D_DIM, D_DIM, D_DIM, D_DIM,
      b_dt, nullptr, 1, 0);
  // 5. Bi/Ci projections
  bc_kernel<<<TOKENS, 256, 0, stream>>>(xbc, W_B, W_C, Bi, Ci);
  // 6. chunked scan: local -> combine -> rescan+gate (writes ybf, xb region dead)
  scan1_kernel<<<dim3(D_DIM / 256, CH, B_DIM), 256, 0, stream>>>(
      dtY, xbc, Bi, A_log, hfin, dtsum);
  scan2_kernel<<<(B_DIM * D_DIM * N_STATE) / 256, 256, 0, stream>>>(
      hfin, dtsum, A_log, hstart);
  scan3_kernel<<<dim3(D_DIM / 256, CH, B_DIM), 256, 0, stream>>>(
      dtY, xbc, Bi, Ci, A_log, hstart, z, D_param, ybf);
  // 7. out = x + y @ W_out   (fp32 out + residual)
  gemm_bf16<<<dim3(H_DIM / BN, TOKENS / BM), 256, 0, stream>>>(
      ybf, W_outT, out, nullptr, 1 << 30, D_DIM, D_DIM, D_DIM, H_DIM,
      nullptr, x, 0, 0);
}

// Round 7
// 678.309 us; speedup vs baseline: 4.2828x; 1.0040x over previous
//
#include <hip/hip_runtime.h>
#include <hip/hip_bf16.h>
#include <cstdint>
#include <cstddef>

#define B_DIM 4
#define L_DIM 2048
#define H_DIM 1024
#define D_DIM 2048
#define N_STATE 16
#define TOKENS (B_DIM * L_DIM)   // 8192
#define CH 16                    // scan chunks
#define LC (L_DIM / CH)          // 128 steps per chunk
#define NEXT 2176                // GEMM2 N: 2048 dt + 32 B/C + 96 pad (17 tiles)

typedef __bf16 bf16x8 __attribute__((ext_vector_type(8)));
typedef float f32x4 __attribute__((ext_vector_type(4)));

__device__ __forceinline__ float sigmoidf_(float x) { return 1.f / (1.f + __expf(-x)); }
__device__ __forceinline__ float softplusf_(float x) {
  return fmaxf(x, 0.f) + log1pf(__expf(-fabsf(x)));
}
__device__ __forceinline__ void gl_lds16(const void* g, void* l) {
  __builtin_amdgcn_global_load_lds(
      (const __attribute__((address_space(1))) unsigned int*)g,
      (__attribute__((address_space(3))) unsigned int*)l, 16, 0, 0);
}

// ---------------- LayerNorm -> bf16: one block per token ----------------
__global__ __launch_bounds__(256) void ln_kernel(const float* __restrict__ x,
    const float* __restrict__ gamma, const float* __restrict__ beta,
    __hip_bfloat16* __restrict__ out) {
  int row = blockIdx.x;
  int t = threadIdx.x;
  const float* px = x + (size_t)row * H_DIM;
  float4 v = *(const float4*)(px + t * 4);
  float s  = v.x + v.y + v.z + v.w;
  float ss = v.x * v.x + v.y * v.y + v.z * v.z + v.w * v.w;
  for (int off = 32; off > 0; off >>= 1) {
    s  += __shfl_down(s, off);
    ss += __shfl_down(ss, off);
  }
  __shared__ float red[8];
  __shared__ float stats[2];
  int wave = t >> 6, lane = t & 63;
  if (lane == 0) { red[wave] = s; red[4 + wave] = ss; }
  __syncthreads();
  if (t == 0) {
    float S  = red[0] + red[1] + red[2] + red[3];
    float SS = red[4] + red[5] + red[6] + red[7];
    float mu = S / H_DIM;
    float var = SS / H_DIM - mu * mu;
    stats[0] = mu;
    stats[1] = rsqrtf(var + 1e-5f);
  }
  __syncthreads();
  float mu = stats[0], rstd = stats[1];
  float4 g  = *(const float4*)(gamma + t * 4);
  float4 bt = *(const float4*)(beta + t * 4);
  __hip_bfloat16* po = out + (size_t)row * H_DIM + t * 4;
  po[0] = __float2bfloat16((v.x - mu) * rstd * g.x + bt.x);
  po[1] = __float2bfloat16((v.y - mu) * rstd * g.y + bt.y);
  po[2] = __float2bfloat16((v.z - mu) * rstd * g.z + bt.z);
  po[3] = __float2bfloat16((v.w - mu) * rstd * g.w + bt.w);
}

// ---------------- transpose+convert: in fp32 [R][C] -> out bf16 [C][R] ----------------
__global__ void transpose_bf16(const float* __restrict__ in,
                               __hip_bfloat16* __restrict__ out, int R, int C) {
  __shared__ float tile[32][33];
  int c0 = blockIdx.x * 32, r0 = blockIdx.y * 32;
  int tx = threadIdx.x, ty = threadIdx.y;   // (32, 8)
  for (int i = 0; i < 32; i += 8)
    tile[ty + i][tx] = in[(size_t)(r0 + ty + i) * C + c0 + tx];
  __syncthreads();
  for (int i = 0; i < 32; i += 8)
    out[(size_t)(c0 + ty + i) * R + r0 + tx] = __float2bfloat16(tile[tx][ty + i]);
}

// ---- W_B/W_C [2048][16] fp32 -> W_ext rows 2048..2079 (bf16, transposed) ----
__global__ __launch_bounds__(256) void wbc_transpose(const float* __restrict__ WB,
    const float* __restrict__ WC, __hip_bfloat16* __restrict__ Wext) {
  int tid = blockIdx.x * 256 + threadIdx.x;   // < 4096
  int c = tid & 31;
  int k0 = (tid >> 5) * 16;
  const float* W = (c < 16) ? WB : WC;
  int cc = c & 15;
  __hip_bfloat16* o = Wext + (size_t)(2048 + c) * D_DIM + k0;
  for (int kk = 0; kk < 16; ++kk)
    o[kk] = __float2bfloat16(W[(size_t)(k0 + kk) * N_STATE + cc]);
}

// ---------------- bf16 MFMA GEMM: C = A[M,K] @ Bt[N,K]^T ----------------
// 128x128 tile, BK=64, XOR-swizzled LDS (0 conflicts), 1D grid with XCD-aware
// swizzle: XCD j (bid%8==j) owns by-rows ≡ j (mod 8) and sweeps bx -> A-panel
// L2-resident per XCD.  Epilogue modes:
//   0: fp32 -> C0 (ldc), + resid
//   1: bf16 split: col<nsplit -> C0, else C1 (ccol=col-nsplit), both ldc
//   2: col<nsplit -> bf16 C0 (ldc) [bias+act apply]; col>=nsplit -> fp32 C1, ld 128
#define BM 128
#define BN 128
#define BK 64

__global__ __launch_bounds__(256) void gemm_bf16(
    const __hip_bfloat16* __restrict__ A, const __hip_bfloat16* __restrict__ Bt,
    void* __restrict__ C0, void* __restrict__ C1, int nsplit,
    int K, int lda, int ldb, int ldc, int gx,
    const float* __restrict__ bias, int nbias,
    const float* __restrict__ resid, int act, int mode) {
  __shared__ __hip_bfloat16 As[BM * BK];   // 16 KB
  __shared__ __hip_bfloat16 Bs[BN * BK];   // 16 KB
  int t = threadIdx.x;
  // XCD-aware swizzle (gy must be divisible by 8)
  int bid = blockIdx.x;
  int nsup = gx << 3;
  int super = bid / nsup;
  int rem = bid - super * nsup;
  int m0 = (super * 8 + (rem & 7)) * BM;
  int n0 = (rem >> 3) * BN;

  int wave = t >> 6, lane = t & 63;
  int quad = lane >> 4, l16 = lane & 15;
  int wm = (wave >> 1) * 64, wn = (wave & 1) * 64;

  f32x4 acc[4][4] = {};

  // staging: 4 issues of 32 rows; thread t -> row j*32+(t>>3), slot (t&7);
  // global chunk cdata = cslot ^ (row&7) (XOR swizzle).
  int srow  = t >> 3;            // 0..31
  int cslot = t & 7;
  int cdata = cslot ^ (srow & 7);
  const __hip_bfloat16* Ag[4];
  const __hip_bfloat16* Bg[4];
  __hip_bfloat16* Asl[4];
  __hip_bfloat16* Bsl[4];
#pragma unroll
  for (int j = 0; j < 4; ++j) {
    Ag[j]  = A  + (size_t)(m0 + j * 32 + srow) * lda + cdata * 8;
    Bg[j]  = Bt + (size_t)(n0 + j * 32 + srow) * ldb + cdata * 8;
    Asl[j] = &As[(j * 32 + srow) * BK + cslot * 8];
    Bsl[j] = &Bs[(j * 32 + srow) * BK + cslot * 8];
  }

  for (int k0 = 0; k0 < K; k0 += BK) {
    __syncthreads();
#pragma unroll
    for (int j = 0; j < 4; ++j) {
      gl_lds16(Ag[j] + k0, Asl[j]);
      gl_lds16(Bg[j] + k0, Bsl[j]);
    }
    __syncthreads();
#pragma unroll
    for (int s = 0; s < 2; ++s) {
      int cs = ((s * 4 + quad) ^ (l16 & 7)) * 8;
      bf16x8 af[4], bf_[4];
#pragma unroll
      for (int i = 0; i < 4; ++i) {
        af[i]  = *(const bf16x8*)&As[(wm + i * 16 + l16) * BK + cs];
        bf_[i] = *(const bf16x8*)&Bs[(wn + i * 16 + l16) * BK + cs];
      }
#pragma unroll
      for (int i = 0; i < 4; ++i)
#pragma unroll
        for (int j = 0; j < 4; ++j)
          acc[i][j] = __builtin_amdgcn_mfma_f32_16x16x32_bf16(af[i], bf_[j], acc[i][j], 0, 0, 0);
    }
  }

#pragma unroll
  for (int i = 0; i < 4; ++i) {
    int row0 = m0 + wm + i * 16 + quad * 4;   // C/D: col=lane&15, row=quad*4+reg
#pragma unroll
    for (int j = 0; j < 4; ++j) {
      int col = n0 + wn + j * 16 + l16;
      f32x4 v = acc[i][j];
      bool mainc = (col < nsplit);
      if (bias && col < nbias) {
        float bb = bias[col];
        v[0] += bb; v[1] += bb; v[2] += bb; v[3] += bb;
      }
      if (act == 1 && (mode != 2 || mainc)) {
        v[0] = softplusf_(v[0]); v[1] = softplusf_(v[1]);
        v[2] = softplusf_(v[2]); v[3] = softplusf_(v[3]);
      }
#pragma unroll
      for (int r = 0; r < 4; ++r) {
        float val = v[r];
        size_t row = row0 + r;
        if (mode == 0) {
          if (resid) val += resid[row * ldc + col];
          ((float*)C0)[row * ldc + col] = val;
        } else if (mode == 1) {
          if (mainc) ((__hip_bfloat16*)C0)[row * ldc + col] = __float2bfloat16(val);
          else       ((__hip_bfloat16*)C1)[row * ldc + (col - nsplit)] = __float2bfloat16(val);
        } else {
          if (mainc) ((__hip_bfloat16*)C0)[row * ldc + col] = __float2bfloat16(val);
          else       ((float*)C1)[row * 128 + (col - nsplit)] = val;
        }
      }
    }
  }
}

// ---------------- depthwise conv(3) + SiLU, bf16 in/out ----------------
__global__ __launch_bounds__(256) void conv_silu_kernel(const __hip_bfloat16* __restrict__ xb,
    const float* __restrict__ cw, const float* __restrict__ cb,
    __hip_bfloat16* __restrict__ xbc) {
  size_t i2 = (size_t)blockIdx.x * 256 + threadIdx.x;  // pair index < TOKENS*D_DIM/2
  int dp = (int)(i2 & (D_DIM / 2 - 1));
  size_t tok = i2 >> 10;
  int l = (int)(tok & (L_DIM - 1));
  int d = dp * 2;
  const __hip_bfloat162* base = (const __hip_bfloat162*)xb + i2;
  __hip_bfloat162 cc = base[0];
  float v0 = cw[d * 3 + 1] * __bfloat162float(cc.x) + cb[d];
  float v1 = cw[d * 3 + 4] * __bfloat162float(cc.y) + cb[d + 1];
  if (l > 0) {
    __hip_bfloat162 pm = base[-(D_DIM / 2)];
    v0 += cw[d * 3 + 0] * __bfloat162float(pm.x);
    v1 += cw[d * 3 + 3] * __bfloat162float(pm.y);
  }
  if (l < L_DIM - 1) {
    __hip_bfloat162 pp = base[D_DIM / 2];
    v0 += cw[d * 3 + 2] * __bfloat162float(pp.x);
    v1 += cw[d * 3 + 5] * __bfloat162float(pp.y);
  }
  v0 = v0 * sigmoidf_(v0);
  v1 = v1 * sigmoidf_(v1);
  __hip_bfloat162 o;
  o.x = __float2bfloat16(v0);
  o.y = __float2bfloat16(v1);
  ((__hip_bfloat162*)xbc)[i2] = o;
}

// ---------------- chunked scan phase 1: one lane per (b,chunk,d), h[16] in regs ----
// BiCi layout: [tok][128] fp32, B = cols 0..15, C = cols 16..31.
__global__ __launch_bounds__(256) void scan1_kernel(const __hip_bfloat16* __restrict__ dt,
    const __hip_bfloat16* __restrict__ xbc, const float* __restrict__ BiCi,
    const float* __restrict__ A_log, float* __restrict__ hfin,
    float* __restrict__ dtsum) {
  __shared__ float Bsh[LC * N_STATE];   // 8 KB
  int t = threadIdx.x;
  int d = blockIdx.x * 256 + t;
  int c = blockIdx.y, b = blockIdx.z;
  size_t base = (size_t)b * L_DIM + (size_t)c * LC;
  for (int idx = t; idx < LC * 4; idx += 256) {
    int row = idx >> 2, q = idx & 3;
    ((float4*)Bsh)[row * 4 + q] = *(const float4*)&BiCi[(base + row) * 128 + q * 4];
  }
  float Aneg[N_STATE];
  {
    const float4* Ap = (const float4*)(A_log + (size_t)d * N_STATE);
#pragma unroll
    for (int q = 0; q < 4; ++q) {
      float4 av = Ap[q];
      Aneg[4 * q + 0] = -__expf(av.x);
      Aneg[4 * q + 1] = -__expf(av.y);
      Aneg[4 * q + 2] = -__expf(av.z);
      Aneg[4 * q + 3] = -__expf(av.w);
    }
  }
  __syncthreads();
  const __hip_bfloat16* dtp = dt + base * D_DIM + d;
  const __hip_bfloat16* xp = xbc + base * D_DIM + d;
  float h[N_STATE];
#pragma unroll
  for (int n = 0; n < N_STATE; ++n) h[n] = 0.f;
  float ds = 0.f;
  float dtv = __bfloat162float(dtp[0]), xv = __bfloat162float(xp[0]);
  for (int i = 0; i < LC; ++i) {
    int ip = (i < LC - 1) ? i + 1 : i;   // clamped prefetch
    float dt2 = __bfloat162float(dtp[(size_t)ip * D_DIM]);
    float x2  = __bfloat162float(xp[(size_t)ip * D_DIM]);
    float dtx = dtv * xv;
    ds += dtv;
    const float4* Brow = (const float4*)&Bsh[i * N_STATE];
#pragma unroll
    for (int q = 0; q < 4; ++q) {
      float4 bv = Brow[q];
      h[4*q+0] = __expf(dtv * Aneg[4*q+0]) * h[4*q+0] + dtx * bv.x;
      h[4*q+1] = __expf(dtv * Aneg[4*q+1]) * h[4*q+1] + dtx * bv.y;
      h[4*q+2] = __expf(dtv * Aneg[4*q+2]) * h[4*q+2] + dtx * bv.z;
      h[4*q+3] = __expf(dtv * Aneg[4*q+3]) * h[4*q+3] + dtx * bv.w;
    }
    dtv = dt2; xv = x2;
  }
  float* ho = hfin + (((size_t)b * CH + c) * D_DIM + d) * N_STATE;
#pragma unroll
  for (int q = 0; q < 4; ++q) {
    float4 v; v.x = h[4*q]; v.y = h[4*q+1]; v.z = h[4*q+2]; v.w = h[4*q+3];
    ((float4*)ho)[q] = v;
  }
  dtsum[((size_t)b * CH + c) * D_DIM + d] = ds;
}

// ---------------- chunked scan phase 2: combine across chunks ----------------
__global__ __launch_bounds__(256) void scan2_kernel(const float* __restrict__ hfin,
    const float* __restrict__ dtsum, const float* __restrict__ A_log,
    float* __restrict__ hstart) {
  int tid = blockIdx.x * 256 + threadIdx.x;   // < B*D*N = 131072
  int n = tid & 15;
  int d = (tid >> 4) & (D_DIM - 1);
  int b = tid >> 15;
  float Aneg = -__expf(A_log[d * N_STATE + n]);
  float run = 0.f;
  for (int c = 0; c < CH; ++c) {
    size_t o = (((size_t)b * CH + c) * D_DIM + d) * N_STATE + n;
    hstart[o] = run;
    run = __expf(Aneg * dtsum[((size_t)b * CH + c) * D_DIM + d]) * run + hfin[o];
  }
}

// ---------------- chunked scan phase 3: rescan + fused gate, h[16] in regs ----------
__global__ __launch_bounds__(256) void scan3_kernel(const __hip_bfloat16* __restrict__ dt,
    const __hip_bfloat16* __restrict__ xbc, const float* __restrict__ BiCi,
    const float* __restrict__ A_log,
    const float* __restrict__ hstart, const __hip_bfloat16* __restrict__ z,
    const float* __restrict__ Dp, __hip_bfloat16* __restrict__ yo) {
  __shared__ float Bsh[LC * N_STATE];   // 8 KB
  __shared__ float Csh[LC * N_STATE];   // 8 KB
  int t = threadIdx.x;
  int d = blockIdx.x * 256 + t;
  int c = blockIdx.y, b = blockIdx.z;
  size_t base = (size_t)b * L_DIM + (size_t)c * LC;
  for (int idx = t; idx < LC * 4; idx += 256) {
    int row = idx >> 2, q = idx & 3;
    ((float4*)Bsh)[row * 4 + q] = *(const float4*)&BiCi[(base + row) * 128 + q * 4];
    ((float4*)Csh)[row * 4 + q] = *(const float4*)&BiCi[(base + row) * 128 + 16 + q * 4];
  }
  float Aneg[N_STATE];
  {
    const float4* Ap = (const float4*)(A_log + (size_t)d * N_STATE);
#pragma unroll
    for (int q = 0; q < 4; ++q) {
      float4 av = Ap[q];
      Aneg[4 * q + 0] = -__expf(av.x);
      Aneg[4 * q + 1] = -__expf(av.y);
      Aneg[4 * q + 2] = -__expf(av.z);
      Aneg[4 * q + 3] = -__expf(av.w);
    }
  }
  float h[N_STATE];
  {
    const float4* hs = (const float4*)(hstart + (((size_t)b * CH + c) * D_DIM + d) * N_STATE);
#pragma unroll
    for (int q = 0; q < 4; ++q) {
      float4 v = hs[q];
      h[4*q] = v.x; h[4*q+1] = v.y; h[4*q+2] = v.z; h[4*q+3] = v.w;
    }
  }
  float Dv = Dp[d];
  __syncthreads();
  const __hip_bfloat16* dtp = dt + base * D_DIM + d;
  const __hip_bfloat16* xp = xbc + base * D_DIM + d;
  const __hip_bfloat16* zp = z + base * D_DIM + d;
  __hip_bfloat16* yp = yo + base * D_DIM + d;
  float dtv = __bfloat162float(dtp[0]), xv = __bfloat162float(xp[0]);
  float zv = __bfloat162float(zp[0]);
  for (int i = 0; i < LC; ++i) {
    int ip = (i < LC - 1) ? i + 1 : i;   // clamped prefetch
    float dt2 = __bfloat162float(dtp[(size_t)ip * D_DIM]);
    float x2  = __bfloat162float(xp[(size_t)ip * D_DIM]);
    float z2  = __bfloat162float(zp[(size_t)ip * D_DIM]);
    float dtx = dtv * xv;
    const float4* Brow = (const float4*)&Bsh[i * N_STATE];
    const float4* Crow = (const float4*)&Csh[i * N_STATE];
    float yv = 0.f;
#pragma unroll
    for (int q = 0; q < 4; ++q) {
      float4 bv = Brow[q];
      float4 cv = Crow[q];
      h[4*q+0] = __expf(dtv * Aneg[4*q+0]) * h[4*q+0] + dtx * bv.x;
      h[4*q+1] = __expf(dtv * Aneg[4*q+1]) * h[4*q+1] + dtx * bv.y;
      h[4*q+2] = __expf(dtv * Aneg[4*q+2]) * h[4*q+2] + dtx * bv.z;
      h[4*q+3] = __expf(dtv * Aneg[4*q+3]) * h[4*q+3] + dtx * bv.w;
      yv += h[4*q+0] * cv.x + h[4*q+1] * cv.y + h[4*q+2] * cv.z + h[4*q+3] * cv.w;
    }
    float g = zv * sigmoidf_(zv);
    yp[(size_t)i * D_DIM] = __float2bfloat16((yv + Dv * xv) * g);
    dtv = dt2; xv = x2; zv = z2;
  }
}

extern "C" void kernel_launch(void* const* d_in, const int* in_sizes, int n_in,
                              void* d_out, int out_size, void* d_ws, size_t ws_size,
                              hipStream_t stream) {
  const float* x          = (const float*)d_in[0];
  const float* norm_scale = (const float*)d_in[1];
  const float* norm_bias  = (const float*)d_in[2];
  const float* W_in       = (const float*)d_in[3];
  const float* conv_w     = (const float*)d_in[4];
  const float* conv_b     = (const float*)d_in[5];
  const float* W_dt       = (const float*)d_in[6];
  const float* b_dt       = (const float*)d_in[7];
  const float* A_log      = (const float*)d_in[8];
  const float* D_param    = (const float*)d_in[9];
  const float* W_B        = (const float*)d_in[10];
  const float* W_C        = (const float*)d_in[11];
  const float* W_out      = (const float*)d_in[12];
  float* out = (float*)d_out;

  // Workspace layout (193 MB, same proven footprint):
  //  S0 [  0, 16M): xn bf16 (dead after GEMM1) -> W_outT [0,4M),
  //                 hfin fp32 [4,12M), dtsum fp32 [12,12.5M)
  //  S1 [ 16, 48M): xb bf16 (GEMM1->conv) -> ybf bf16 (scan3 -> GEMM3)
  //  S2 [ 48, 80M): z bf16 (GEMM1->scan3)
  //  S3 [ 80,112M): xbc bf16 (conv->scan)
  //  S4 [112,144M): dt bf16 (GEMM2 main out -> scan)
  //     [144,148M): BiCi fp32 [8192][128] (GEMM2 split out -> scan)
  //     [148,157M): W_ext bf16 [2176][2048] (transposes -> GEMM2)
  //  S6 [177,185M): W_inT bf16 (dead after GEMM1) -> hstart fp32 (8M)
  const size_t MB = 1024 * 1024;
  const size_t NEEDED = 193 * MB;
  if (ws_size < NEEDED) return;   // diagnostic bail: ws too small

  char* ws = (char*)d_ws;
  __hip_bfloat16* xn     = (__hip_bfloat16*)(ws);
  __hip_bfloat16* W_outT = (__hip_bfloat16*)(ws);            // [0,4M) after xn dead
  float*          hfin   = (float*)(ws + 4 * MB);            // [4,12M)
  float*          dtsum  = (float*)(ws + 12 * MB);           // [12,12.5M)
  __hip_bfloat16* xb     = (__hip_bfloat16*)(ws + 16 * MB);
  __hip_bfloat16* ybf    = (__hip_bfloat16*)(ws + 16 * MB);  // after conv
  __hip_bfloat16* z      = (__hip_bfloat16*)(ws + 48 * MB);
  __hip_bfloat16* xbc    = (__hip_bfloat16*)(ws + 80 * MB);
  __hip_bfloat16* dtY    = (__hip_bfloat16*)(ws + 112 * MB);
  float*          BiCi   = (float*)(ws + 144 * MB);
  __hip_bfloat16* W_ext  = (__hip_bfloat16*)(ws + 148 * MB);
  __hip_bfloat16* W_inT  = (__hip_bfloat16*)(ws + 177 * MB);
  float*          hstart = (float*)(ws + 177 * MB);          // after W_inT dead

  dim3 tb(32, 8);
  // 0. weight transpose+convert
  transpose_bf16<<<dim3(4096 / 32, 1024 / 32), tb, 0, stream>>>(W_in, W_inT, 1024, 4096);
  transpose_bf16<<<dim3(2048 / 32, 2048 / 32), tb, 0, stream>>>(W_dt, W_ext, 2048, 2048);
  wbc_transpose<<<16, 256, 0, stream>>>(W_B, W_C, W_ext);
  // 1. LayerNorm -> bf16
  ln_kernel<<<TOKENS, 256, 0, stream>>>(x, norm_scale, norm_bias, xn);
  // 2. merged [xb|z] = xn @ W_in  (N=4096, mode 1 split)
  gemm_bf16<<<(4096 / BN) * (TOKENS / BM), 256, 0, stream>>>(
      xn, W_inT, xb, z, D_DIM, H_DIM, H_DIM, H_DIM, D_DIM, 4096 / BN,
      nullptr, 0, nullptr, 0, 1);
  // (xn dead) convert W_out into S0
  transpose_bf16<<<dim3(1024 / 32, 2048 / 32), tb, 0, stream>>>(W_out, W_outT, 2048, 1024);
  // 3. depthwise conv + silu -> xbc bf16
  conv_silu_kernel<<<(TOKENS * D_DIM / 2) / 256, 256, 0, stream>>>(xb, conv_w, conv_b, xbc);
  // 4. fused: [dt | Bi | Ci] = xbc @ W_ext  (mode 2: dt bf16 + BiCi fp32)
  gemm_bf16<<<(NEXT / BN) * (TOKENS / BM), 256, 0, stream>>>(
      xbc, W_ext, dtY, BiCi, D_DIM, D_DIM, D_DIM, D_DIM, D_DIM, NEXT / BN,
      b_dt, D_DIM, nullptr, 1, 2);
  // 5. chunked scan: local -> combine -> rescan+gate (writes ybf, xb region dead)
  scan1_kernel<<<dim3(D_DIM / 256, CH, B_DIM), 256, 0, stream>>>(
      dtY, xbc, BiCi, A_log, hfin, dtsum);
  scan2_kernel<<<(B_DIM * D_DIM * N_STATE) / 256, 256, 0, stream>>>(
      hfin, dtsum, A_log, hstart);
  scan3_kernel<<<dim3(D_DIM / 256, CH, B_DIM), 256, 0, stream>>>(
      dtY, xbc, BiCi, A_log, hstart, z, D_param, ybf);
  // 6. out = x + y @ W_out   (mode 0: fp32 + residual)
  gemm_bf16<<<(H_DIM / BN) * (TOKENS / BM), 256, 0, stream>>>(
      ybf, W_outT, out, nullptr, 1 << 30, D_DIM, D_DIM, D_DIM, H_DIM, H_DIM / BN,
      nullptr, 0, x, 0, 0);
}

// Round 8
// 650.464 us; speedup vs baseline: 4.4662x; 1.0428x over previous
//
#include <hip/hip_runtime.h>
#include <hip/hip_bf16.h>
#include <cstdint>
#include <cstddef>

#define B_DIM 4
#define L_DIM 2048
#define H_DIM 1024
#define D_DIM 2048
#define N_STATE 16
#define TOKENS (B_DIM * L_DIM)   // 8192
#define CH 16                    // scan chunks
#define LC (L_DIM / CH)          // 128 steps per chunk
#define NEXT 2176                // GEMM2 N: 2048 dt + 32 B/C + 96 pad (17 tiles)

typedef __bf16 bf16x8 __attribute__((ext_vector_type(8)));
typedef float f32x4 __attribute__((ext_vector_type(4)));

__device__ __forceinline__ float sigmoidf_(float x) { return 1.f / (1.f + __expf(-x)); }
__device__ __forceinline__ float softplusf_(float x) {
  return fmaxf(x, 0.f) + log1pf(__expf(-fabsf(x)));
}
__device__ __forceinline__ void gl_lds16(const void* g, void* l) {
  __builtin_amdgcn_global_load_lds(
      (const __attribute__((address_space(1))) unsigned int*)g,
      (__attribute__((address_space(3))) unsigned int*)l, 16, 0, 0);
}

// ---------------- LayerNorm -> bf16: one block per token ----------------
__global__ __launch_bounds__(256) void ln_kernel(const float* __restrict__ x,
    const float* __restrict__ gamma, const float* __restrict__ beta,
    __hip_bfloat16* __restrict__ out) {
  int row = blockIdx.x;
  int t = threadIdx.x;
  const float* px = x + (size_t)row * H_DIM;
  float4 v = *(const float4*)(px + t * 4);
  float s  = v.x + v.y + v.z + v.w;
  float ss = v.x * v.x + v.y * v.y + v.z * v.z + v.w * v.w;
  for (int off = 32; off > 0; off >>= 1) {
    s  += __shfl_down(s, off);
    ss += __shfl_down(ss, off);
  }
  __shared__ float red[8];
  __shared__ float stats[2];
  int wave = t >> 6, lane = t & 63;
  if (lane == 0) { red[wave] = s; red[4 + wave] = ss; }
  __syncthreads();
  if (t == 0) {
    float S  = red[0] + red[1] + red[2] + red[3];
    float SS = red[4] + red[5] + red[6] + red[7];
    float mu = S / H_DIM;
    float var = SS / H_DIM - mu * mu;
    stats[0] = mu;
    stats[1] = rsqrtf(var + 1e-5f);
  }
  __syncthreads();
  float mu = stats[0], rstd = stats[1];
  float4 g  = *(const float4*)(gamma + t * 4);
  float4 bt = *(const float4*)(beta + t * 4);
  __hip_bfloat16* po = out + (size_t)row * H_DIM + t * 4;
  po[0] = __float2bfloat16((v.x - mu) * rstd * g.x + bt.x);
  po[1] = __float2bfloat16((v.y - mu) * rstd * g.y + bt.y);
  po[2] = __float2bfloat16((v.z - mu) * rstd * g.z + bt.z);
  po[3] = __float2bfloat16((v.w - mu) * rstd * g.w + bt.w);
}

// ---------------- transpose+convert: in fp32 [R][C] -> out bf16 [C][R] ----------------
__global__ void transpose_bf16(const float* __restrict__ in,
                               __hip_bfloat16* __restrict__ out, int R, int C) {
  __shared__ float tile[32][33];
  int c0 = blockIdx.x * 32, r0 = blockIdx.y * 32;
  int tx = threadIdx.x, ty = threadIdx.y;   // (32, 8)
  for (int i = 0; i < 32; i += 8)
    tile[ty + i][tx] = in[(size_t)(r0 + ty + i) * C + c0 + tx];
  __syncthreads();
  for (int i = 0; i < 32; i += 8)
    out[(size_t)(c0 + ty + i) * R + r0 + tx] = __float2bfloat16(tile[tx][ty + i]);
}

// ---- W_B/W_C [2048][16] fp32 -> W_ext rows 2048..2079 (bf16, transposed) ----
__global__ __launch_bounds__(256) void wbc_transpose(const float* __restrict__ WB,
    const float* __restrict__ WC, __hip_bfloat16* __restrict__ Wext) {
  int tid = blockIdx.x * 256 + threadIdx.x;   // < 4096
  int c = tid & 31;
  int k0 = (tid >> 5) * 16;
  const float* W = (c < 16) ? WB : WC;
  int cc = c & 15;
  __hip_bfloat16* o = Wext + (size_t)(2048 + c) * D_DIM + k0;
  for (int kk = 0; kk < 16; ++kk)
    o[kk] = __float2bfloat16(W[(size_t)(k0 + kk) * N_STATE + cc]);
}

// ---------------- bf16 MFMA GEMM: C = A[M,K] @ Bt[N,K]^T ----------------
// 128x128 tile, BK=64, XOR-swizzled LDS (0 conflicts), 1D grid with XCD-aware
// swizzle (XCD j owns by ≡ j mod 8, sweeps bx -> A-panel L2-resident per XCD).
// Templated epilogue (one mode per instantiation -> minimal VGPR):
//   MODE 0: fp32 -> C0 (ldc), + resid
//   MODE 1: bf16 split: col<nsplit -> C0, else C1 (col-nsplit), both ldc
//   MODE 2: col<nsplit -> softplus(+bias) bf16 C0 (ldc); else fp32 C1, ld 128
#define BM 128
#define BN 128
#define BK 64

template <int MODE>
__global__ __launch_bounds__(256) void gemm_bf16(
    const __hip_bfloat16* __restrict__ A, const __hip_bfloat16* __restrict__ Bt,
    void* __restrict__ C0, void* __restrict__ C1, int nsplit,
    int K, int lda, int ldb, int ldc, int gx,
    const float* __restrict__ bias, const float* __restrict__ resid) {
  __shared__ __hip_bfloat16 As[BM * BK];   // 16 KB
  __shared__ __hip_bfloat16 Bs[BN * BK];   // 16 KB
  int t = threadIdx.x;
  // XCD-aware swizzle (grid-y count must be divisible by 8)
  int bid = blockIdx.x;
  int nsup = gx << 3;
  int super = bid / nsup;
  int rem = bid - super * nsup;
  int m0 = (super * 8 + (rem & 7)) * BM;
  int n0 = (rem >> 3) * BN;

  int wave = t >> 6, lane = t & 63;
  int quad = lane >> 4, l16 = lane & 15;
  int wm = (wave >> 1) * 64, wn = (wave & 1) * 64;

  f32x4 acc[4][4] = {};

  // staging: 4 issues of 32 rows; thread t -> row j*32+(t>>3), slot (t&7);
  // global chunk cdata = cslot ^ (row&7) (XOR swizzle).
  int srow  = t >> 3;            // 0..31
  int cslot = t & 7;
  int cdata = cslot ^ (srow & 7);
  const __hip_bfloat16* Ag[4];
  const __hip_bfloat16* Bg[4];
  __hip_bfloat16* Asl[4];
  __hip_bfloat16* Bsl[4];
#pragma unroll
  for (int j = 0; j < 4; ++j) {
    Ag[j]  = A  + (size_t)(m0 + j * 32 + srow) * lda + cdata * 8;
    Bg[j]  = Bt + (size_t)(n0 + j * 32 + srow) * ldb + cdata * 8;
    Asl[j] = &As[(j * 32 + srow) * BK + cslot * 8];
    Bsl[j] = &Bs[(j * 32 + srow) * BK + cslot * 8];
  }

  for (int k0 = 0; k0 < K; k0 += BK) {
    __syncthreads();
#pragma unroll
    for (int j = 0; j < 4; ++j) {
      gl_lds16(Ag[j] + k0, Asl[j]);
      gl_lds16(Bg[j] + k0, Bsl[j]);
    }
    __syncthreads();
#pragma unroll
    for (int s = 0; s < 2; ++s) {
      int cs = ((s * 4 + quad) ^ (l16 & 7)) * 8;
      bf16x8 af[4], bf_[4];
#pragma unroll
      for (int i = 0; i < 4; ++i) {
        af[i]  = *(const bf16x8*)&As[(wm + i * 16 + l16) * BK + cs];
        bf_[i] = *(const bf16x8*)&Bs[(wn + i * 16 + l16) * BK + cs];
      }
#pragma unroll
      for (int i = 0; i < 4; ++i)
#pragma unroll
        for (int j = 0; j < 4; ++j)
          acc[i][j] = __builtin_amdgcn_mfma_f32_16x16x32_bf16(af[i], bf_[j], acc[i][j], 0, 0, 0);
    }
  }

#pragma unroll
  for (int i = 0; i < 4; ++i) {
    int row0 = m0 + wm + i * 16 + quad * 4;   // C/D: col=lane&15, row=quad*4+reg
#pragma unroll
    for (int j = 0; j < 4; ++j) {
      int col = n0 + wn + j * 16 + l16;
      f32x4 v = acc[i][j];
      if (MODE == 0) {
#pragma unroll
        for (int r = 0; r < 4; ++r) {
          size_t idx = (size_t)(row0 + r) * ldc + col;
          ((float*)C0)[idx] = v[r] + resid[idx];
        }
      } else if (MODE == 1) {
        bool mainc = (col < nsplit);
        __hip_bfloat16* cb = mainc ? (__hip_bfloat16*)C0 : (__hip_bfloat16*)C1;
        int ccol = mainc ? col : col - nsplit;
#pragma unroll
        for (int r = 0; r < 4; ++r)
          cb[(size_t)(row0 + r) * ldc + ccol] = __float2bfloat16(v[r]);
      } else {
        if (col < nsplit) {
          float bb = bias[col];
#pragma unroll
          for (int r = 0; r < 4; ++r)
            ((__hip_bfloat16*)C0)[(size_t)(row0 + r) * ldc + col] =
                __float2bfloat16(softplusf_(v[r] + bb));
        } else {
#pragma unroll
          for (int r = 0; r < 4; ++r)
            ((float*)C1)[(size_t)(row0 + r) * 128 + (col - nsplit)] = v[r];
        }
      }
    }
  }
}

// ---------------- depthwise conv(3) + SiLU, bf16 in/out ----------------
__global__ __launch_bounds__(256) void conv_silu_kernel(const __hip_bfloat16* __restrict__ xb,
    const float* __restrict__ cw, const float* __restrict__ cb,
    __hip_bfloat16* __restrict__ xbc) {
  size_t i2 = (size_t)blockIdx.x * 256 + threadIdx.x;  // pair index < TOKENS*D_DIM/2
  int dp = (int)(i2 & (D_DIM / 2 - 1));
  size_t tok = i2 >> 10;
  int l = (int)(tok & (L_DIM - 1));
  int d = dp * 2;
  const __hip_bfloat162* base = (const __hip_bfloat162*)xb + i2;
  __hip_bfloat162 cc = base[0];
  float v0 = cw[d * 3 + 1] * __bfloat162float(cc.x) + cb[d];
  float v1 = cw[d * 3 + 4] * __bfloat162float(cc.y) + cb[d + 1];
  if (l > 0) {
    __hip_bfloat162 pm = base[-(D_DIM / 2)];
    v0 += cw[d * 3 + 0] * __bfloat162float(pm.x);
    v1 += cw[d * 3 + 3] * __bfloat162float(pm.y);
  }
  if (l < L_DIM - 1) {
    __hip_bfloat162 pp = base[D_DIM / 2];
    v0 += cw[d * 3 + 2] * __bfloat162float(pp.x);
    v1 += cw[d * 3 + 5] * __bfloat162float(pp.y);
  }
  v0 = v0 * sigmoidf_(v0);
  v1 = v1 * sigmoidf_(v1);
  __hip_bfloat162 o;
  o.x = __float2bfloat16(v0);
  o.y = __float2bfloat16(v1);
  ((__hip_bfloat162*)xbc)[i2] = o;
}

// ---------------- chunked scan phase 1: one lane per (b,chunk,d), h[16] in regs ----
// BiCi layout: [tok][128] fp32, B = cols 0..15, C = cols 16..31.
__global__ __launch_bounds__(256) void scan1_kernel(const __hip_bfloat16* __restrict__ dt,
    const __hip_bfloat16* __restrict__ xbc, const float* __restrict__ BiCi,
    const float* __restrict__ A_log, float* __restrict__ hfin,
    float* __restrict__ dtsum) {
  __shared__ float Bsh[LC * N_STATE];   // 8 KB
  int t = threadIdx.x;
  int d = blockIdx.x * 256 + t;
  int c = blockIdx.y, b = blockIdx.z;
  size_t base = (size_t)b * L_DIM + (size_t)c * LC;
  for (int idx = t; idx < LC * 4; idx += 256) {
    int row = idx >> 2, q = idx & 3;
    ((float4*)Bsh)[row * 4 + q] = *(const float4*)&BiCi[(base + row) * 128 + q * 4];
  }
  float Aneg[N_STATE];
  {
    const float4* Ap = (const float4*)(A_log + (size_t)d * N_STATE);
#pragma unroll
    for (int q = 0; q < 4; ++q) {
      float4 av = Ap[q];
      Aneg[4 * q + 0] = -__expf(av.x);
      Aneg[4 * q + 1] = -__expf(av.y);
      Aneg[4 * q + 2] = -__expf(av.z);
      Aneg[4 * q + 3] = -__expf(av.w);
    }
  }
  __syncthreads();
  const __hip_bfloat16* dtp = dt + base * D_DIM + d;
  const __hip_bfloat16* xp = xbc + base * D_DIM + d;
  float h[N_STATE];
#pragma unroll
  for (int n = 0; n < N_STATE; ++n) h[n] = 0.f;
  float ds = 0.f;
  float dtv = __bfloat162float(dtp[0]), xv = __bfloat162float(xp[0]);
  for (int i = 0; i < LC; ++i) {
    int ip = (i < LC - 1) ? i + 1 : i;   // clamped prefetch
    float dt2 = __bfloat162float(dtp[(size_t)ip * D_DIM]);
    float x2  = __bfloat162float(xp[(size_t)ip * D_DIM]);
    float dtx = dtv * xv;
    ds += dtv;
    const float4* Brow = (const float4*)&Bsh[i * N_STATE];
#pragma unroll
    for (int q = 0; q < 4; ++q) {
      float4 bv = Brow[q];
      h[4*q+0] = __expf(dtv * Aneg[4*q+0]) * h[4*q+0] + dtx * bv.x;
      h[4*q+1] = __expf(dtv * Aneg[4*q+1]) * h[4*q+1] + dtx * bv.y;
      h[4*q+2] = __expf(dtv * Aneg[4*q+2]) * h[4*q+2] + dtx * bv.z;
      h[4*q+3] = __expf(dtv * Aneg[4*q+3]) * h[4*q+3] + dtx * bv.w;
    }
    dtv = dt2; xv = x2;
  }
  float* ho = hfin + (((size_t)b * CH + c) * D_DIM + d) * N_STATE;
#pragma unroll
  for (int q = 0; q < 4; ++q) {
    float4 v; v.x = h[4*q]; v.y = h[4*q+1]; v.z = h[4*q+2]; v.w = h[4*q+3];
    ((float4*)ho)[q] = v;
  }
  dtsum[((size_t)b * CH + c) * D_DIM + d] = ds;
}

// ---------------- chunked scan phase 2: combine across chunks ----------------
__global__ __launch_bounds__(256) void scan2_kernel(const float* __restrict__ hfin,
    const float* __restrict__ dtsum, const float* __restrict__ A_log,
    float* __restrict__ hstart) {
  int tid = blockIdx.x * 256 + threadIdx.x;   // < B*D*N = 131072
  int n = tid & 15;
  int d = (tid >> 4) & (D_DIM - 1);
  int b = tid >> 15;
  float Aneg = -__expf(A_log[d * N_STATE + n]);
  float run = 0.f;
  for (int c = 0; c < CH; ++c) {
    size_t o = (((size_t)b * CH + c) * D_DIM + d) * N_STATE + n;
    hstart[o] = run;
    run = __expf(Aneg * dtsum[((size_t)b * CH + c) * D_DIM + d]) * run + hfin[o];
  }
}

// ---------------- chunked scan phase 3: rescan + fused gate, h[16] in regs ----------
__global__ __launch_bounds__(256) void scan3_kernel(const __hip_bfloat16* __restrict__ dt,
    const __hip_bfloat16* __restrict__ xbc, const float* __restrict__ BiCi,
    const float* __restrict__ A_log,
    const float* __restrict__ hstart, const __hip_bfloat16* __restrict__ z,
    const float* __restrict__ Dp, __hip_bfloat16* __restrict__ yo) {
  __shared__ float Bsh[LC * N_STATE];   // 8 KB
  __shared__ float Csh[LC * N_STATE];   // 8 KB
  int t = threadIdx.x;
  int d = blockIdx.x * 256 + t;
  int c = blockIdx.y, b = blockIdx.z;
  size_t base = (size_t)b * L_DIM + (size_t)c * LC;
  for (int idx = t; idx < LC * 4; idx += 256) {
    int row = idx >> 2, q = idx & 3;
    ((float4*)Bsh)[row * 4 + q] = *(const float4*)&BiCi[(base + row) * 128 + q * 4];
    ((float4*)Csh)[row * 4 + q] = *(const float4*)&BiCi[(base + row) * 128 + 16 + q * 4];
  }
  float Aneg[N_STATE];
  {
    const float4* Ap = (const float4*)(A_log + (size_t)d * N_STATE);
#pragma unroll
    for (int q = 0; q < 4; ++q) {
      float4 av = Ap[q];
      Aneg[4 * q + 0] = -__expf(av.x);
      Aneg[4 * q + 1] = -__expf(av.y);
      Aneg[4 * q + 2] = -__expf(av.z);
      Aneg[4 * q + 3] = -__expf(av.w);
    }
  }
  float h[N_STATE];
  {
    const float4* hs = (const float4*)(hstart + (((size_t)b * CH + c) * D_DIM + d) * N_STATE);
#pragma unroll
    for (int q = 0; q < 4; ++q) {
      float4 v = hs[q];
      h[4*q] = v.x; h[4*q+1] = v.y; h[4*q+2] = v.z; h[4*q+3] = v.w;
    }
  }
  float Dv = Dp[d];
  __syncthreads();
  const __hip_bfloat16* dtp = dt + base * D_DIM + d;
  const __hip_bfloat16* xp = xbc + base * D_DIM + d;
  const __hip_bfloat16* zp = z + base * D_DIM + d;
  __hip_bfloat16* yp = yo + base * D_DIM + d;
  float dtv = __bfloat162float(dtp[0]), xv = __bfloat162float(xp[0]);
  float zv = __bfloat162float(zp[0]);
  for (int i = 0; i < LC; ++i) {
    int ip = (i < LC - 1) ? i + 1 : i;   // clamped prefetch
    float dt2 = __bfloat162float(dtp[(size_t)ip * D_DIM]);
    float x2  = __bfloat162float(xp[(size_t)ip * D_DIM]);
    float z2  = __bfloat162float(zp[(size_t)ip * D_DIM]);
    float dtx = dtv * xv;
    const float4* Brow = (const float4*)&Bsh[i * N_STATE];
    const float4* Crow = (const float4*)&Csh[i * N_STATE];
    float yv = 0.f;
#pragma unroll
    for (int q = 0; q < 4; ++q) {
      float4 bv = Brow[q];
      float4 cv = Crow[q];
      h[4*q+0] = __expf(dtv * Aneg[4*q+0]) * h[4*q+0] + dtx * bv.x;
      h[4*q+1] = __expf(dtv * Aneg[4*q+1]) * h[4*q+1] + dtx * bv.y;
      h[4*q+2] = __expf(dtv * Aneg[4*q+2]) * h[4*q+2] + dtx * bv.z;
      h[4*q+3] = __expf(dtv * Aneg[4*q+3]) * h[4*q+3] + dtx * bv.w;
      yv += h[4*q+0] * cv.x + h[4*q+1] * cv.y + h[4*q+2] * cv.z + h[4*q+3] * cv.w;
    }
    float g = zv * sigmoidf_(zv);
    yp[(size_t)i * D_DIM] = __float2bfloat16((yv + Dv * xv) * g);
    dtv = dt2; xv = x2; zv = z2;
  }
}

extern "C" void kernel_launch(void* const* d_in, const int* in_sizes, int n_in,
                              void* d_out, int out_size, void* d_ws, size_t ws_size,
                              hipStream_t stream) {
  const float* x          = (const float*)d_in[0];
  const float* norm_scale = (const float*)d_in[1];
  const float* norm_bias  = (const float*)d_in[2];
  const float* W_in       = (const float*)d_in[3];
  const float* conv_w     = (const float*)d_in[4];
  const float* conv_b     = (const float*)d_in[5];
  const float* W_dt       = (const float*)d_in[6];
  const float* b_dt       = (const float*)d_in[7];
  const float* A_log      = (const float*)d_in[8];
  const float* D_param    = (const float*)d_in[9];
  const float* W_B        = (const float*)d_in[10];
  const float* W_C        = (const float*)d_in[11];
  const float* W_out      = (const float*)d_in[12];
  float* out = (float*)d_out;

  // Workspace layout (193 MB, same proven footprint as R7):
  //  S0 [  0, 16M): xn bf16 (dead after GEMM1) -> W_outT [0,4M),
  //                 hfin fp32 [4,12M), dtsum fp32 [12,12.5M)
  //  S1 [ 16, 48M): xb bf16 (GEMM1->conv) -> ybf bf16 (scan3 -> GEMM3)
  //  S2 [ 48, 80M): z bf16 (GEMM1->scan3)
  //  S3 [ 80,112M): xbc bf16 (conv->scan)
  //  S4 [112,144M): dt bf16 (GEMM2 main out -> scan)
  //     [144,148M): BiCi fp32 [8192][128] (GEMM2 split out -> scan)
  //     [148,157M): W_ext bf16 [2176][2048] (transposes -> GEMM2)
  //  S6 [177,185M): W_inT bf16 (dead after GEMM1) -> hstart fp32 (8M)
  const size_t MB = 1024 * 1024;
  const size_t NEEDED = 193 * MB;
  if (ws_size < NEEDED) return;   // diagnostic bail: ws too small

  char* ws = (char*)d_ws;
  __hip_bfloat16* xn     = (__hip_bfloat16*)(ws);
  __hip_bfloat16* W_outT = (__hip_bfloat16*)(ws);            // [0,4M) after xn dead
  float*          hfin   = (float*)(ws + 4 * MB);            // [4,12M)
  float*          dtsum  = (float*)(ws + 12 * MB);           // [12,12.5M)
  __hip_bfloat16* xb     = (__hip_bfloat16*)(ws + 16 * MB);
  __hip_bfloat16* ybf    = (__hip_bfloat16*)(ws + 16 * MB);  // after conv
  __hip_bfloat16* z      = (__hip_bfloat16*)(ws + 48 * MB);
  __hip_bfloat16* xbc    = (__hip_bfloat16*)(ws + 80 * MB);
  __hip_bfloat16* dtY    = (__hip_bfloat16*)(ws + 112 * MB);
  float*          BiCi   = (float*)(ws + 144 * MB);
  __hip_bfloat16* W_ext  = (__hip_bfloat16*)(ws + 148 * MB);
  __hip_bfloat16* W_inT  = (__hip_bfloat16*)(ws + 177 * MB);
  float*          hstart = (float*)(ws + 177 * MB);          // after W_inT dead

  dim3 tb(32, 8);
  // 0. weight transpose+convert
  transpose_bf16<<<dim3(4096 / 32, 1024 / 32), tb, 0, stream>>>(W_in, W_inT, 1024, 4096);
  transpose_bf16<<<dim3(2048 / 32, 2048 / 32), tb, 0, stream>>>(W_dt, W_ext, 2048, 2048);
  wbc_transpose<<<16, 256, 0, stream>>>(W_B, W_C, W_ext);
  // 1. LayerNorm -> bf16
  ln_kernel<<<TOKENS, 256, 0, stream>>>(x, norm_scale, norm_bias, xn);
  // 2. merged [xb|z] = xn @ W_in  (MODE 1 split)
  gemm_bf16<1><<<(4096 / BN) * (TOKENS / BM), 256, 0, stream>>>(
      xn, W_inT, xb, z, D_DIM, H_DIM, H_DIM, H_DIM, D_DIM, 4096 / BN,
      nullptr, nullptr);
  // (xn dead) convert W_out into S0
  transpose_bf16<<<dim3(1024 / 32, 2048 / 32), tb, 0, stream>>>(W_out, W_outT, 2048, 1024);
  // 3. depthwise conv + silu -> xbc bf16
  conv_silu_kernel<<<(TOKENS * D_DIM / 2) / 256, 256, 0, stream>>>(xb, conv_w, conv_b, xbc);
  // 4. fused: [dt | Bi | Ci] = xbc @ W_ext  (MODE 2: dt bf16+softplus, BiCi fp32)
  gemm_bf16<2><<<(NEXT / BN) * (TOKENS / BM), 256, 0, stream>>>(
      xbc, W_ext, dtY, BiCi, D_DIM, D_DIM, D_DIM, D_DIM, D_DIM, NEXT / BN,
      b_dt, nullptr);
  // 5. chunked scan: local -> combine -> rescan+gate (writes ybf, xb region dead)
  scan1_kernel<<<dim3(D_DIM / 256, CH, B_DIM), 256, 0, stream>>>(
      dtY, xbc, BiCi, A_log, hfin, dtsum);
  scan2_kernel<<<(B_DIM * D_DIM * N_STATE) / 256, 256, 0, stream>>>(
      hfin, dtsum, A_log, hstart);
  scan3_kernel<<<dim3(D_DIM / 256, CH, B_DIM), 256, 0, stream>>>(
      dtY, xbc, BiCi, A_log, hstart, z, D_param, ybf);
  // 6. out = x + y @ W_out   (MODE 0: fp32 + residual)
  gemm_bf16<0><<<(H_DIM / BN) * (TOKENS / BM), 256, 0, stream>>>(
      ybf, W_outT, out, nullptr, 1 << 30, D_DIM, D_DIM, D_DIM, H_DIM, H_DIM / BN,
      nullptr, x);
}